// Round 4
// baseline (651.515 us; speedup 1.0000x reference)
//
#include <hip/hip_runtime.h>
#include <hip/hip_bf16.h>
#include <math.h>

// ---------------------------------------------------------------------------
// Problem constants (from reference)
// ---------------------------------------------------------------------------
#define N_NODES 50000
#define N_EDGES 800000
#define NFEAT   512
#define NHID    256
#define NCLASS  128
#define N_UV    2048

typedef __bf16 bf16x8 __attribute__((ext_vector_type(8)));
typedef short  s16x8  __attribute__((ext_vector_type(8)));
typedef float  f32x4  __attribute__((ext_vector_type(4)));

__device__ __forceinline__ unsigned short bf16_rn(float f) {
  unsigned u = __float_as_uint(f);
  u += 0x7fffu + ((u >> 16) & 1u);
  return (unsigned short)(u >> 16);
}
__device__ __forceinline__ float bf16_to_f(unsigned short h) {
  return __uint_as_float(((unsigned)h) << 16);
}

// ---------------------------------------------------------------------------
// Split-bf16 MFMA GEMM: C[M,N] = A[M,K] @ BT[N,K]^T  (fp32-quality via
// Ahi*Bhi + Ahi*Blo + Alo*Bhi). 128x128 tile, BK=32, 256 thr, 4 waves 2x2,
// each wave 4x4 tiles of mfma_f32_16x16x32_bf16.
// 2-stage register pipeline: prefetch tile k+1 into VGPRs during compute of
// tile k (single LDS buffer, 2 barriers/iter). 40KB LDS -> 4 blocks/CU.
// ASPLIT/BSPLIT: that operand arrives fp32 and is hi/lo-split during staging.
// ---------------------------------------------------------------------------
#define LDSPAD 40   // 32 + 8 shorts: keeps 16B alignment, breaks pow2 stride

template <bool ASPLIT, bool BSPLIT, bool SIGMOID>
__global__ __launch_bounds__(256, 4) void gemm_mfma_split(
    const float* __restrict__ Af,
    const unsigned short* __restrict__ Ahi, const unsigned short* __restrict__ Alo,
    const float* __restrict__ BTf,
    const unsigned short* __restrict__ BThi, const unsigned short* __restrict__ BTlo,
    float* __restrict__ C, int M, int N, int K) {
  __shared__ unsigned short sAh[128 * LDSPAD];
  __shared__ unsigned short sAl[128 * LDSPAD];
  __shared__ unsigned short sBh[128 * LDSPAD];
  __shared__ unsigned short sBl[128 * LDSPAD];

  const int tid  = threadIdx.x;
  const int lane = tid & 63;
  const int wave = tid >> 6;
  const int wm   = (wave >> 1) << 6;
  const int wn   = (wave & 1) << 6;
  const int lm   = lane & 15;
  const int quad = lane >> 4;
  const int m0   = blockIdx.y * 128;
  const int n0   = blockIdx.x * 128;

  // staging coordinates
  const int r32 = tid >> 3;            // 0..31 (fp32 path: 32 rows/pass)
  const int c32 = (tid & 7) * 4;       // float4 col
  const int r16 = tid >> 2;            // 0..63 (bf16 path: 64 rows/pass)
  const int c16 = (tid & 3) * 8;       // s16x8 col

  // prefetch registers
  float4 pA[4]; s16x8 pAh[2], pAl[2];
  float4 pB[4]; s16x8 pBh[2], pBl[2];

  f32x4 acc[4][4];
#pragma unroll
  for (int i = 0; i < 4; ++i)
#pragma unroll
    for (int j = 0; j < 4; ++j)
#pragma unroll
      for (int r = 0; r < 4; ++r) acc[i][j][r] = 0.f;

#define LOAD_TILE(k0)                                                          \
  do {                                                                         \
    if (ASPLIT) {                                                              \
      _Pragma("unroll") for (int p = 0; p < 4; ++p) {                          \
        const int m = m0 + p * 32 + r32;                                       \
        pA[p] = make_float4(0.f, 0.f, 0.f, 0.f);                               \
        if (m < M) pA[p] = *(const float4*)&Af[(size_t)m * K + (k0) + c32];    \
      }                                                                        \
    } else {                                                                   \
      _Pragma("unroll") for (int p = 0; p < 2; ++p) {                          \
        const int m = m0 + p * 64 + r16;                                       \
        _Pragma("unroll") for (int e = 0; e < 8; ++e) { pAh[p][e] = 0; pAl[p][e] = 0; } \
        if (m < M) {                                                           \
          pAh[p] = *(const s16x8*)&Ahi[(size_t)m * K + (k0) + c16];            \
          pAl[p] = *(const s16x8*)&Alo[(size_t)m * K + (k0) + c16];            \
        }                                                                      \
      }                                                                        \
    }                                                                          \
    if (BSPLIT) {                                                              \
      _Pragma("unroll") for (int p = 0; p < 4; ++p)                            \
        pB[p] = *(const float4*)&BTf[(size_t)(n0 + p * 32 + r32) * K + (k0) + c32]; \
    } else {                                                                   \
      _Pragma("unroll") for (int p = 0; p < 2; ++p) {                          \
        pBh[p] = *(const s16x8*)&BThi[(size_t)(n0 + p * 64 + r16) * K + (k0) + c16]; \
        pBl[p] = *(const s16x8*)&BTlo[(size_t)(n0 + p * 64 + r16) * K + (k0) + c16]; \
      }                                                                        \
    }                                                                          \
  } while (0)

#define SPLIT4(v, hv, lv)                                                      \
  hv.x = bf16_rn(v.x); lv.x = bf16_rn(v.x - bf16_to_f(hv.x));                  \
  hv.y = bf16_rn(v.y); lv.y = bf16_rn(v.y - bf16_to_f(hv.y));                  \
  hv.z = bf16_rn(v.z); lv.z = bf16_rn(v.z - bf16_to_f(hv.z));                  \
  hv.w = bf16_rn(v.w); lv.w = bf16_rn(v.w - bf16_to_f(hv.w));

#define STORE_TILE()                                                           \
  do {                                                                         \
    if (ASPLIT) {                                                              \
      _Pragma("unroll") for (int p = 0; p < 4; ++p) {                          \
        ushort4 hv, lv; SPLIT4(pA[p], hv, lv);                                 \
        const int row = p * 32 + r32;                                          \
        *(ushort4*)&sAh[row * LDSPAD + c32] = hv;                              \
        *(ushort4*)&sAl[row * LDSPAD + c32] = lv;                              \
      }                                                                        \
    } else {                                                                   \
      _Pragma("unroll") for (int p = 0; p < 2; ++p) {                          \
        const int row = p * 64 + r16;                                          \
        *(s16x8*)&sAh[row * LDSPAD + c16] = pAh[p];                            \
        *(s16x8*)&sAl[row * LDSPAD + c16] = pAl[p];                            \
      }                                                                        \
    }                                                                          \
    if (BSPLIT) {                                                              \
      _Pragma("unroll") for (int p = 0; p < 4; ++p) {                          \
        ushort4 hv, lv; SPLIT4(pB[p], hv, lv);                                 \
        const int row = p * 32 + r32;                                          \
        *(ushort4*)&sBh[row * LDSPAD + c32] = hv;                              \
        *(ushort4*)&sBl[row * LDSPAD + c32] = lv;                              \
      }                                                                        \
    } else {                                                                   \
      _Pragma("unroll") for (int p = 0; p < 2; ++p) {                          \
        const int row = p * 64 + r16;                                          \
        *(s16x8*)&sBh[row * LDSPAD + c16] = pBh[p];                            \
        *(s16x8*)&sBl[row * LDSPAD + c16] = pBl[p];                            \
      }                                                                        \
    }                                                                          \
  } while (0)

  LOAD_TILE(0);

  for (int k0 = 0; k0 < K; k0 += 32) {
    if (k0) __syncthreads();      // WAR: prior iter's frag reads complete
    STORE_TILE();
    __syncthreads();              // RAW: stores visible
    if (k0 + 32 < K) LOAD_TILE(k0 + 32);   // prefetch next tile (latency hidden)

    bf16x8 aH[4], aL[4], bH[4], bL[4];
#pragma unroll
    for (int i = 0; i < 4; ++i) {
      const int r = wm + i * 16 + lm;
      aH[i] = __builtin_bit_cast(bf16x8, *(const s16x8*)&sAh[r * LDSPAD + quad * 8]);
      aL[i] = __builtin_bit_cast(bf16x8, *(const s16x8*)&sAl[r * LDSPAD + quad * 8]);
    }
#pragma unroll
    for (int j = 0; j < 4; ++j) {
      const int r = wn + j * 16 + lm;
      bH[j] = __builtin_bit_cast(bf16x8, *(const s16x8*)&sBh[r * LDSPAD + quad * 8]);
      bL[j] = __builtin_bit_cast(bf16x8, *(const s16x8*)&sBl[r * LDSPAD + quad * 8]);
    }
#pragma unroll
    for (int i = 0; i < 4; ++i)
#pragma unroll
      for (int j = 0; j < 4; ++j) {
        acc[i][j] = __builtin_amdgcn_mfma_f32_16x16x32_bf16(aH[i], bH[j], acc[i][j], 0, 0, 0);
        acc[i][j] = __builtin_amdgcn_mfma_f32_16x16x32_bf16(aH[i], bL[j], acc[i][j], 0, 0, 0);
        acc[i][j] = __builtin_amdgcn_mfma_f32_16x16x32_bf16(aL[i], bH[j], acc[i][j], 0, 0, 0);
      }
  }

  // ---- epilogue: C/D layout col=lane&15, row=quad*4+reg ----
#pragma unroll
  for (int i = 0; i < 4; ++i)
#pragma unroll
    for (int j = 0; j < 4; ++j) {
      const int col = n0 + wn + j * 16 + lm;
#pragma unroll
      for (int r = 0; r < 4; ++r) {
        const int row = m0 + wm + i * 16 + quad * 4 + r;
        if (row < M) {
          float v = acc[i][j][r];
          if (SIGMOID) v = 1.f / (1.f + expf(-v));
          C[(size_t)row * N + col] = v;
        }
      }
    }
#undef LOAD_TILE
#undef STORE_TILE
#undef SPLIT4
}

// ---------------------------------------------------------------------------
// Weight prep: T[n*K+k] = split(W[k*N+n])
// ---------------------------------------------------------------------------
__global__ __launch_bounds__(256) void split_transpose(
    const float* __restrict__ W, unsigned short* __restrict__ Thi,
    unsigned short* __restrict__ Tlo, int K, int N) {
  const int idx = blockIdx.x * 256 + threadIdx.x;
  if (idx >= K * N) return;
  const int n = idx / K;
  const int k = idx - n * K;
  const float f = W[(size_t)k * N + n];
  const unsigned short h = bf16_rn(f);
  Thi[idx] = h;
  Tlo[idx] = bf16_rn(f - bf16_to_f(h));
}

// ---------------------------------------------------------------------------
// row_ptr[n] = lower_bound(rows, n); rows sorted. Edge-parallel build.
// ---------------------------------------------------------------------------
__global__ __launch_bounds__(256) void build_row_ptr(
    const int* __restrict__ rows, int* __restrict__ row_ptr) {
  const int e = blockIdx.x * 256 + threadIdx.x;
  if (e >= N_EDGES) return;
  const int r = rows[e];
  const int rprev = (e == 0) ? -1 : rows[e - 1];
  for (int n = rprev + 1; n <= r; ++n) row_ptr[n] = e;
  if (e == N_EDGES - 1) {
    for (int n = r + 1; n <= N_NODES; ++n) row_ptr[n] = N_EDGES;
  }
}

// ---------------------------------------------------------------------------
// SpMM F=256: one wave per node, lane covers 4 feats (float4), 4-edge unroll.
// Fused relu + bf16 hi/lo split output.
// ---------------------------------------------------------------------------
__global__ __launch_bounds__(256) void spmm256_split(
    const float4* __restrict__ S4, const int* __restrict__ row_ptr,
    const int* __restrict__ cols, const float* __restrict__ vals,
    const float4* __restrict__ bias4,
    unsigned short* __restrict__ outHi, unsigned short* __restrict__ outLo) {
  const int wave = threadIdx.x >> 6;
  const int lane = threadIdx.x & 63;
  const int node = blockIdx.x * 4 + wave;

  const int lo = row_ptr[node];
  const int hi = row_ptr[node + 1];

  float4 acc = make_float4(0.f, 0.f, 0.f, 0.f);
  int e = lo;
  for (; e + 4 <= hi; e += 4) {
    const int c0 = cols[e + 0], c1 = cols[e + 1], c2 = cols[e + 2], c3 = cols[e + 3];
    const float w0 = vals[e + 0], w1 = vals[e + 1], w2 = vals[e + 2], w3 = vals[e + 3];
    const float4 r0 = S4[(size_t)c0 * 64 + lane];
    const float4 r1 = S4[(size_t)c1 * 64 + lane];
    const float4 r2 = S4[(size_t)c2 * 64 + lane];
    const float4 r3 = S4[(size_t)c3 * 64 + lane];
    acc.x = fmaf(w0, r0.x, acc.x); acc.y = fmaf(w0, r0.y, acc.y);
    acc.z = fmaf(w0, r0.z, acc.z); acc.w = fmaf(w0, r0.w, acc.w);
    acc.x = fmaf(w1, r1.x, acc.x); acc.y = fmaf(w1, r1.y, acc.y);
    acc.z = fmaf(w1, r1.z, acc.z); acc.w = fmaf(w1, r1.w, acc.w);
    acc.x = fmaf(w2, r2.x, acc.x); acc.y = fmaf(w2, r2.y, acc.y);
    acc.z = fmaf(w2, r2.z, acc.z); acc.w = fmaf(w2, r2.w, acc.w);
    acc.x = fmaf(w3, r3.x, acc.x); acc.y = fmaf(w3, r3.y, acc.y);
    acc.z = fmaf(w3, r3.z, acc.z); acc.w = fmaf(w3, r3.w, acc.w);
  }
  for (; e < hi; ++e) {
    const int c = cols[e];
    const float w = vals[e];
    const float4 r = S4[(size_t)c * 64 + lane];
    acc.x = fmaf(w, r.x, acc.x); acc.y = fmaf(w, r.y, acc.y);
    acc.z = fmaf(w, r.z, acc.z); acc.w = fmaf(w, r.w, acc.w);
  }

  const float4 b = bias4[lane];
  acc.x = fmaxf(acc.x + b.x, 0.f);
  acc.y = fmaxf(acc.y + b.y, 0.f);
  acc.z = fmaxf(acc.z + b.z, 0.f);
  acc.w = fmaxf(acc.w + b.w, 0.f);

  ushort4 hv, lv;
  hv.x = bf16_rn(acc.x); lv.x = bf16_rn(acc.x - bf16_to_f(hv.x));
  hv.y = bf16_rn(acc.y); lv.y = bf16_rn(acc.y - bf16_to_f(hv.y));
  hv.z = bf16_rn(acc.z); lv.z = bf16_rn(acc.z - bf16_to_f(hv.z));
  hv.w = bf16_rn(acc.w); lv.w = bf16_rn(acc.w - bf16_to_f(hv.w));
  const size_t o = (size_t)node * NHID + lane * 4;
  *(ushort4*)&outHi[o] = hv;
  *(ushort4*)&outLo[o] = lv;
}

// ---------------------------------------------------------------------------
// SpMM F=128: one wave per node; half-waves process alternating edges with
// float4, 2-edge unroll per half, shfl_xor combine.
// ---------------------------------------------------------------------------
__global__ __launch_bounds__(256) void spmm128_f32(
    const float4* __restrict__ S4, const int* __restrict__ row_ptr,
    const int* __restrict__ cols, const float* __restrict__ vals,
    const float4* __restrict__ bias4, float4* __restrict__ out4) {
  const int wave = threadIdx.x >> 6;
  const int lane = threadIdx.x & 63;
  const int half = lane >> 5;
  const int l32  = lane & 31;
  const int node = blockIdx.x * 4 + wave;

  const int lo = row_ptr[node];
  const int hi = row_ptr[node + 1];

  float4 acc = make_float4(0.f, 0.f, 0.f, 0.f);
  int e = lo + half;
  for (; e + 2 < hi; e += 4) {
    const int c0 = cols[e], c1 = cols[e + 2];
    const float w0 = vals[e], w1 = vals[e + 2];
    const float4 r0 = S4[(size_t)c0 * 32 + l32];
    const float4 r1 = S4[(size_t)c1 * 32 + l32];
    acc.x = fmaf(w0, r0.x, acc.x); acc.y = fmaf(w0, r0.y, acc.y);
    acc.z = fmaf(w0, r0.z, acc.z); acc.w = fmaf(w0, r0.w, acc.w);
    acc.x = fmaf(w1, r1.x, acc.x); acc.y = fmaf(w1, r1.y, acc.y);
    acc.z = fmaf(w1, r1.z, acc.z); acc.w = fmaf(w1, r1.w, acc.w);
  }
  for (; e < hi; e += 2) {
    const int c = cols[e];
    const float w = vals[e];
    const float4 r = S4[(size_t)c * 32 + l32];
    acc.x = fmaf(w, r.x, acc.x); acc.y = fmaf(w, r.y, acc.y);
    acc.z = fmaf(w, r.z, acc.z); acc.w = fmaf(w, r.w, acc.w);
  }

  acc.x += __shfl_xor(acc.x, 32);
  acc.y += __shfl_xor(acc.y, 32);
  acc.z += __shfl_xor(acc.z, 32);
  acc.w += __shfl_xor(acc.w, 32);

  if (half == 0) {
    const float4 b = bias4[l32];
    acc.x += b.x; acc.y += b.y; acc.z += b.z; acc.w += b.w;
    out4[(size_t)node * 32 + l32] = acc;
  }
}

// ---------------------------------------------------------------------------
// Head helper: row gather (128 feats)
// ---------------------------------------------------------------------------
__global__ __launch_bounds__(128) void gather_rows(
    const float* __restrict__ Z, const int* __restrict__ idx,
    float* __restrict__ out) {
  out[blockIdx.x * NCLASS + threadIdx.x] =
      Z[(size_t)idx[blockIdx.x] * NCLASS + threadIdx.x];
}

// ---------------------------------------------------------------------------
// Launch
// ---------------------------------------------------------------------------
extern "C" void kernel_launch(void* const* d_in, const int* in_sizes, int n_in,
                              void* d_out, int out_size, void* d_ws, size_t ws_size,
                              hipStream_t stream) {
  const int*   u       = (const int*)  d_in[0];
  const int*   v       = (const int*)  d_in[1];
  const float* x       = (const float*)d_in[2];
  const int*   adj_row = (const int*)  d_in[3];
  const int*   adj_col = (const int*)  d_in[4];
  const float* adj_val = (const float*)d_in[5];
  const float* W1      = (const float*)d_in[6];
  const float* b1      = (const float*)d_in[7];
  const float* W2      = (const float*)d_in[8];
  const float* b2      = (const float*)d_in[9];
  const float* We      = (const float*)d_in[10];
  float* out = (float*)d_out;

  char* wsb = (char*)d_ws;
  // Region A [0, 51.2MB): S1; after spmm1 dead -> S2 [0,25.6) + Z [25.6,51.2)
  float* S1 = (float*)wsb;
  float* S2 = (float*)wsb;
  float* Z  = (float*)(wsb + (size_t)N_NODES * NCLASS * sizeof(float));
  // Region B [51.2MB, 102.4MB): Hhi/Hlo; after GEMM2 dead -> head scratch
  char* rB = wsb + (size_t)N_NODES * NHID * sizeof(float);
  unsigned short* Hhi = (unsigned short*)rB;
  unsigned short* Hlo = Hhi + (size_t)N_NODES * NHID;
  float* ZUG = (float*)rB;                 // 2048*128
  float* ZV  = ZUG + N_UV * NCLASS;        // 2048*128
  float* ZU  = ZV + N_UV * NCLASS;         // 2048*128
  // Split weights + row_ptr parked in d_out (dead until the final GEMM)
  unsigned short* W1Thi = (unsigned short*)out;
  unsigned short* W1Tlo = W1Thi + NHID * NFEAT;
  unsigned short* W2Thi = W1Tlo + NHID * NFEAT;
  unsigned short* W2Tlo = W2Thi + NCLASS * NHID;
  int* row_ptr = (int*)(W2Tlo + NCLASS * NHID);   // 50001 ints

  // 0) weight prep + row_ptr build
  split_transpose<<<(NFEAT * NHID + 255) / 256, 256, 0, stream>>>(W1, W1Thi, W1Tlo, NFEAT, NHID);
  split_transpose<<<(NHID * NCLASS + 255) / 256, 256, 0, stream>>>(W2, W2Thi, W2Tlo, NHID, NCLASS);
  build_row_ptr<<<(N_EDGES + 255) / 256, 256, 0, stream>>>(adj_row, row_ptr);

  // 1) S1 = x @ W1  (MFMA split-bf16, A split on the fly)
  gemm_mfma_split<true, false, false><<<dim3(NHID / 128, (N_NODES + 127) / 128), 256, 0, stream>>>(
      x, nullptr, nullptr, nullptr, W1Thi, W1Tlo, S1, N_NODES, NHID, NFEAT);

  // 2) Hhi/Hlo = split(relu(A @ S1 + b1))
  spmm256_split<<<N_NODES / 4, 256, 0, stream>>>(
      (const float4*)S1, row_ptr, adj_col, adj_val, (const float4*)b1, Hhi, Hlo);

  // 3) S2 = H @ W2  (MFMA split-bf16, A pre-split)
  gemm_mfma_split<false, false, false><<<dim3(NCLASS / 128, (N_NODES + 127) / 128), 256, 0, stream>>>(
      nullptr, Hhi, Hlo, nullptr, W2Thi, W2Tlo, S2, N_NODES, NCLASS, NHID);

  // 4) Z = A @ S2 + b2
  spmm128_f32<<<N_NODES / 4, 256, 0, stream>>>(
      (const float4*)S2, row_ptr, adj_col, adj_val, (const float4*)b2, (float4*)Z);

  // 5) head gathers: ZUG = Z[u], ZV = Z[v]
  gather_rows<<<N_UV, NCLASS, 0, stream>>>(Z, u, ZUG);
  gather_rows<<<N_UV, NCLASS, 0, stream>>>(Z, v, ZV);

  // 6) ZU = ZUG @ We^T   (BT = We as stored; both operands split on the fly)
  gemm_mfma_split<true, true, false><<<dim3(NCLASS / 128, N_UV / 128), 256, 0, stream>>>(
      ZUG, nullptr, nullptr, We, nullptr, nullptr, ZU, N_UV, NCLASS, NCLASS);

  // 7) out = sigmoid(ZU @ ZV^T)
  gemm_mfma_split<true, true, true><<<dim3(N_UV / 128, N_UV / 128), 256, 0, stream>>>(
      ZU, nullptr, nullptr, ZV, nullptr, nullptr, out, N_UV, N_UV, NCLASS);
}

// Round 5
// 429.712 us; speedup vs baseline: 1.5162x; 1.5162x over previous
//
#include <hip/hip_runtime.h>
#include <hip/hip_bf16.h>
#include <math.h>

// ---------------------------------------------------------------------------
// Problem constants (from reference)
// ---------------------------------------------------------------------------
#define N_NODES 50000
#define N_EDGES 800000
#define NFEAT   512
#define NHID    256
#define NCLASS  128
#define N_UV    2048

typedef __bf16 bf16x8 __attribute__((ext_vector_type(8)));
typedef short  s16x8  __attribute__((ext_vector_type(8)));
typedef float  f32x4  __attribute__((ext_vector_type(4)));

__device__ __forceinline__ unsigned short bf16_rn(float f) {
  unsigned u = __float_as_uint(f);
  u += 0x7fffu + ((u >> 16) & 1u);
  return (unsigned short)(u >> 16);
}
__device__ __forceinline__ float bf16_to_f(unsigned short h) {
  return __uint_as_float(((unsigned)h) << 16);
}

// ---------------------------------------------------------------------------
// Split-bf16 MFMA GEMM: C[M,N] = A[M,K] @ BT[N,K]^T  (fp32-quality via
// Ahi*Bhi + Ahi*Blo + Alo*Bhi). 128x128 tile, BK=32, 256 thr, 4 waves 2x2,
// each wave 4x4 tiles of mfma_f32_16x16x32_bf16.
// 2-stage register pipeline: prefetch tile k+1 into VGPRs during compute of
// tile k (single LDS buffer, 2 barriers/iter).
// launch_bounds(256,2): VGPR cap 256/wave — acc(64)+prefetch(32)+frags(64)
// +addressing fits WITHOUT spill. (256,4) capped at 128 and spilled 387MB to
// scratch (round-4 regression: WRITE_SIZE 50->387MB, dur 135->241us).
// ---------------------------------------------------------------------------
#define LDSPAD 40   // 32 + 8 shorts: keeps 16B alignment, breaks pow2 stride

template <bool ASPLIT, bool BSPLIT, bool SIGMOID>
__global__ __launch_bounds__(256, 2) void gemm_mfma_split(
    const float* __restrict__ Af,
    const unsigned short* __restrict__ Ahi, const unsigned short* __restrict__ Alo,
    const float* __restrict__ BTf,
    const unsigned short* __restrict__ BThi, const unsigned short* __restrict__ BTlo,
    float* __restrict__ C, int M, int N, int K) {
  __shared__ unsigned short sAh[128 * LDSPAD];
  __shared__ unsigned short sAl[128 * LDSPAD];
  __shared__ unsigned short sBh[128 * LDSPAD];
  __shared__ unsigned short sBl[128 * LDSPAD];

  const int tid  = threadIdx.x;
  const int lane = tid & 63;
  const int wave = tid >> 6;
  const int wm   = (wave >> 1) << 6;
  const int wn   = (wave & 1) << 6;
  const int lm   = lane & 15;
  const int quad = lane >> 4;
  const int m0   = blockIdx.y * 128;
  const int n0   = blockIdx.x * 128;

  // staging coordinates
  const int r32 = tid >> 3;            // 0..31 (fp32 path: 32 rows/pass)
  const int c32 = (tid & 7) * 4;       // float4 col
  const int r16 = tid >> 2;            // 0..63 (bf16 path: 64 rows/pass)
  const int c16 = (tid & 3) * 8;       // s16x8 col

  // prefetch registers
  float4 pA[4]; s16x8 pAh[2], pAl[2];
  float4 pB[4]; s16x8 pBh[2], pBl[2];

  f32x4 acc[4][4];
#pragma unroll
  for (int i = 0; i < 4; ++i)
#pragma unroll
    for (int j = 0; j < 4; ++j)
#pragma unroll
      for (int r = 0; r < 4; ++r) acc[i][j][r] = 0.f;

#define LOAD_TILE(k0)                                                          \
  do {                                                                         \
    if (ASPLIT) {                                                              \
      _Pragma("unroll") for (int p = 0; p < 4; ++p) {                          \
        const int m = m0 + p * 32 + r32;                                       \
        pA[p] = make_float4(0.f, 0.f, 0.f, 0.f);                               \
        if (m < M) pA[p] = *(const float4*)&Af[(size_t)m * K + (k0) + c32];    \
      }                                                                        \
    } else {                                                                   \
      _Pragma("unroll") for (int p = 0; p < 2; ++p) {                          \
        const int m = m0 + p * 64 + r16;                                       \
        _Pragma("unroll") for (int e = 0; e < 8; ++e) { pAh[p][e] = 0; pAl[p][e] = 0; } \
        if (m < M) {                                                           \
          pAh[p] = *(const s16x8*)&Ahi[(size_t)m * K + (k0) + c16];            \
          pAl[p] = *(const s16x8*)&Alo[(size_t)m * K + (k0) + c16];            \
        }                                                                      \
      }                                                                        \
    }                                                                          \
    if (BSPLIT) {                                                              \
      _Pragma("unroll") for (int p = 0; p < 4; ++p)                            \
        pB[p] = *(const float4*)&BTf[(size_t)(n0 + p * 32 + r32) * K + (k0) + c32]; \
    } else {                                                                   \
      _Pragma("unroll") for (int p = 0; p < 2; ++p) {                          \
        pBh[p] = *(const s16x8*)&BThi[(size_t)(n0 + p * 64 + r16) * K + (k0) + c16]; \
        pBl[p] = *(const s16x8*)&BTlo[(size_t)(n0 + p * 64 + r16) * K + (k0) + c16]; \
      }                                                                        \
    }                                                                          \
  } while (0)

#define SPLIT4(v, hv, lv)                                                      \
  hv.x = bf16_rn(v.x); lv.x = bf16_rn(v.x - bf16_to_f(hv.x));                  \
  hv.y = bf16_rn(v.y); lv.y = bf16_rn(v.y - bf16_to_f(hv.y));                  \
  hv.z = bf16_rn(v.z); lv.z = bf16_rn(v.z - bf16_to_f(hv.z));                  \
  hv.w = bf16_rn(v.w); lv.w = bf16_rn(v.w - bf16_to_f(hv.w));

#define STORE_TILE()                                                           \
  do {                                                                         \
    if (ASPLIT) {                                                              \
      _Pragma("unroll") for (int p = 0; p < 4; ++p) {                          \
        ushort4 hv, lv; SPLIT4(pA[p], hv, lv);                                 \
        const int row = p * 32 + r32;                                          \
        *(ushort4*)&sAh[row * LDSPAD + c32] = hv;                              \
        *(ushort4*)&sAl[row * LDSPAD + c32] = lv;                              \
      }                                                                        \
    } else {                                                                   \
      _Pragma("unroll") for (int p = 0; p < 2; ++p) {                          \
        const int row = p * 64 + r16;                                          \
        *(s16x8*)&sAh[row * LDSPAD + c16] = pAh[p];                            \
        *(s16x8*)&sAl[row * LDSPAD + c16] = pAl[p];                            \
      }                                                                        \
    }                                                                          \
    if (BSPLIT) {                                                              \
      _Pragma("unroll") for (int p = 0; p < 4; ++p) {                          \
        ushort4 hv, lv; SPLIT4(pB[p], hv, lv);                                 \
        const int row = p * 32 + r32;                                          \
        *(ushort4*)&sBh[row * LDSPAD + c32] = hv;                              \
        *(ushort4*)&sBl[row * LDSPAD + c32] = lv;                              \
      }                                                                        \
    } else {                                                                   \
      _Pragma("unroll") for (int p = 0; p < 2; ++p) {                          \
        const int row = p * 64 + r16;                                          \
        *(s16x8*)&sBh[row * LDSPAD + c16] = pBh[p];                            \
        *(s16x8*)&sBl[row * LDSPAD + c16] = pBl[p];                            \
      }                                                                        \
    }                                                                          \
  } while (0)

  LOAD_TILE(0);

  for (int k0 = 0; k0 < K; k0 += 32) {
    if (k0) __syncthreads();      // WAR: prior iter's frag reads complete
    STORE_TILE();
    __syncthreads();              // RAW: stores visible
    if (k0 + 32 < K) LOAD_TILE(k0 + 32);   // prefetch next tile (latency hidden)

    bf16x8 aH[4], aL[4], bH[4], bL[4];
#pragma unroll
    for (int i = 0; i < 4; ++i) {
      const int r = wm + i * 16 + lm;
      aH[i] = __builtin_bit_cast(bf16x8, *(const s16x8*)&sAh[r * LDSPAD + quad * 8]);
      aL[i] = __builtin_bit_cast(bf16x8, *(const s16x8*)&sAl[r * LDSPAD + quad * 8]);
    }
#pragma unroll
    for (int j = 0; j < 4; ++j) {
      const int r = wn + j * 16 + lm;
      bH[j] = __builtin_bit_cast(bf16x8, *(const s16x8*)&sBh[r * LDSPAD + quad * 8]);
      bL[j] = __builtin_bit_cast(bf16x8, *(const s16x8*)&sBl[r * LDSPAD + quad * 8]);
    }
#pragma unroll
    for (int i = 0; i < 4; ++i)
#pragma unroll
      for (int j = 0; j < 4; ++j) {
        acc[i][j] = __builtin_amdgcn_mfma_f32_16x16x32_bf16(aH[i], bH[j], acc[i][j], 0, 0, 0);
        acc[i][j] = __builtin_amdgcn_mfma_f32_16x16x32_bf16(aH[i], bL[j], acc[i][j], 0, 0, 0);
        acc[i][j] = __builtin_amdgcn_mfma_f32_16x16x32_bf16(aL[i], bH[j], acc[i][j], 0, 0, 0);
      }
  }

  // ---- epilogue: C/D layout col=lane&15, row=quad*4+reg ----
#pragma unroll
  for (int i = 0; i < 4; ++i)
#pragma unroll
    for (int j = 0; j < 4; ++j) {
      const int col = n0 + wn + j * 16 + lm;
#pragma unroll
      for (int r = 0; r < 4; ++r) {
        const int row = m0 + wm + i * 16 + quad * 4 + r;
        if (row < M) {
          float v = acc[i][j][r];
          if (SIGMOID) v = 1.f / (1.f + expf(-v));
          C[(size_t)row * N + col] = v;
        }
      }
    }
#undef LOAD_TILE
#undef STORE_TILE
#undef SPLIT4
}

// ---------------------------------------------------------------------------
// Weight prep: T[n*K+k] = split(W[k*N+n])
// ---------------------------------------------------------------------------
__global__ __launch_bounds__(256) void split_transpose(
    const float* __restrict__ W, unsigned short* __restrict__ Thi,
    unsigned short* __restrict__ Tlo, int K, int N) {
  const int idx = blockIdx.x * 256 + threadIdx.x;
  if (idx >= K * N) return;
  const int n = idx / K;
  const int k = idx - n * K;
  const float f = W[(size_t)k * N + n];
  const unsigned short h = bf16_rn(f);
  Thi[idx] = h;
  Tlo[idx] = bf16_rn(f - bf16_to_f(h));
}

// ---------------------------------------------------------------------------
// row_ptr[n] = lower_bound(rows, n); rows sorted. Edge-parallel build.
// ---------------------------------------------------------------------------
__global__ __launch_bounds__(256) void build_row_ptr(
    const int* __restrict__ rows, int* __restrict__ row_ptr) {
  const int e = blockIdx.x * 256 + threadIdx.x;
  if (e >= N_EDGES) return;
  const int r = rows[e];
  const int rprev = (e == 0) ? -1 : rows[e - 1];
  for (int n = rprev + 1; n <= r; ++n) row_ptr[n] = e;
  if (e == N_EDGES - 1) {
    for (int n = r + 1; n <= N_NODES; ++n) row_ptr[n] = N_EDGES;
  }
}

// ---------------------------------------------------------------------------
// SpMM F=256: one wave per node, lane covers 4 feats (float4), 4-edge unroll.
// Fused relu + bf16 hi/lo split output.
// ---------------------------------------------------------------------------
__global__ __launch_bounds__(256) void spmm256_split(
    const float4* __restrict__ S4, const int* __restrict__ row_ptr,
    const int* __restrict__ cols, const float* __restrict__ vals,
    const float4* __restrict__ bias4,
    unsigned short* __restrict__ outHi, unsigned short* __restrict__ outLo) {
  const int wave = threadIdx.x >> 6;
  const int lane = threadIdx.x & 63;
  const int node = blockIdx.x * 4 + wave;

  const int lo = row_ptr[node];
  const int hi = row_ptr[node + 1];

  float4 acc = make_float4(0.f, 0.f, 0.f, 0.f);
  int e = lo;
  for (; e + 4 <= hi; e += 4) {
    const int c0 = cols[e + 0], c1 = cols[e + 1], c2 = cols[e + 2], c3 = cols[e + 3];
    const float w0 = vals[e + 0], w1 = vals[e + 1], w2 = vals[e + 2], w3 = vals[e + 3];
    const float4 r0 = S4[(size_t)c0 * 64 + lane];
    const float4 r1 = S4[(size_t)c1 * 64 + lane];
    const float4 r2 = S4[(size_t)c2 * 64 + lane];
    const float4 r3 = S4[(size_t)c3 * 64 + lane];
    acc.x = fmaf(w0, r0.x, acc.x); acc.y = fmaf(w0, r0.y, acc.y);
    acc.z = fmaf(w0, r0.z, acc.z); acc.w = fmaf(w0, r0.w, acc.w);
    acc.x = fmaf(w1, r1.x, acc.x); acc.y = fmaf(w1, r1.y, acc.y);
    acc.z = fmaf(w1, r1.z, acc.z); acc.w = fmaf(w1, r1.w, acc.w);
    acc.x = fmaf(w2, r2.x, acc.x); acc.y = fmaf(w2, r2.y, acc.y);
    acc.z = fmaf(w2, r2.z, acc.z); acc.w = fmaf(w2, r2.w, acc.w);
    acc.x = fmaf(w3, r3.x, acc.x); acc.y = fmaf(w3, r3.y, acc.y);
    acc.z = fmaf(w3, r3.z, acc.z); acc.w = fmaf(w3, r3.w, acc.w);
  }
  for (; e < hi; ++e) {
    const int c = cols[e];
    const float w = vals[e];
    const float4 r = S4[(size_t)c * 64 + lane];
    acc.x = fmaf(w, r.x, acc.x); acc.y = fmaf(w, r.y, acc.y);
    acc.z = fmaf(w, r.z, acc.z); acc.w = fmaf(w, r.w, acc.w);
  }

  const float4 b = bias4[lane];
  acc.x = fmaxf(acc.x + b.x, 0.f);
  acc.y = fmaxf(acc.y + b.y, 0.f);
  acc.z = fmaxf(acc.z + b.z, 0.f);
  acc.w = fmaxf(acc.w + b.w, 0.f);

  ushort4 hv, lv;
  hv.x = bf16_rn(acc.x); lv.x = bf16_rn(acc.x - bf16_to_f(hv.x));
  hv.y = bf16_rn(acc.y); lv.y = bf16_rn(acc.y - bf16_to_f(hv.y));
  hv.z = bf16_rn(acc.z); lv.z = bf16_rn(acc.z - bf16_to_f(hv.z));
  hv.w = bf16_rn(acc.w); lv.w = bf16_rn(acc.w - bf16_to_f(hv.w));
  const size_t o = (size_t)node * NHID + lane * 4;
  *(ushort4*)&outHi[o] = hv;
  *(ushort4*)&outLo[o] = lv;
}

// ---------------------------------------------------------------------------
// SpMM F=128: one wave per node; half-waves process alternating edges with
// float4, 2-edge unroll per half, shfl_xor combine.
// ---------------------------------------------------------------------------
__global__ __launch_bounds__(256) void spmm128_f32(
    const float4* __restrict__ S4, const int* __restrict__ row_ptr,
    const int* __restrict__ cols, const float* __restrict__ vals,
    const float4* __restrict__ bias4, float4* __restrict__ out4) {
  const int wave = threadIdx.x >> 6;
  const int lane = threadIdx.x & 63;
  const int half = lane >> 5;
  const int l32  = lane & 31;
  const int node = blockIdx.x * 4 + wave;

  const int lo = row_ptr[node];
  const int hi = row_ptr[node + 1];

  float4 acc = make_float4(0.f, 0.f, 0.f, 0.f);
  int e = lo + half;
  for (; e + 2 < hi; e += 4) {
    const int c0 = cols[e], c1 = cols[e + 2];
    const float w0 = vals[e], w1 = vals[e + 2];
    const float4 r0 = S4[(size_t)c0 * 32 + l32];
    const float4 r1 = S4[(size_t)c1 * 32 + l32];
    acc.x = fmaf(w0, r0.x, acc.x); acc.y = fmaf(w0, r0.y, acc.y);
    acc.z = fmaf(w0, r0.z, acc.z); acc.w = fmaf(w0, r0.w, acc.w);
    acc.x = fmaf(w1, r1.x, acc.x); acc.y = fmaf(w1, r1.y, acc.y);
    acc.z = fmaf(w1, r1.z, acc.z); acc.w = fmaf(w1, r1.w, acc.w);
  }
  for (; e < hi; e += 2) {
    const int c = cols[e];
    const float w = vals[e];
    const float4 r = S4[(size_t)c * 32 + l32];
    acc.x = fmaf(w, r.x, acc.x); acc.y = fmaf(w, r.y, acc.y);
    acc.z = fmaf(w, r.z, acc.z); acc.w = fmaf(w, r.w, acc.w);
  }

  acc.x += __shfl_xor(acc.x, 32);
  acc.y += __shfl_xor(acc.y, 32);
  acc.z += __shfl_xor(acc.z, 32);
  acc.w += __shfl_xor(acc.w, 32);

  if (half == 0) {
    const float4 b = bias4[l32];
    acc.x += b.x; acc.y += b.y; acc.z += b.z; acc.w += b.w;
    out4[(size_t)node * 32 + l32] = acc;
  }
}

// ---------------------------------------------------------------------------
// Head helper: row gather (128 feats)
// ---------------------------------------------------------------------------
__global__ __launch_bounds__(128) void gather_rows(
    const float* __restrict__ Z, const int* __restrict__ idx,
    float* __restrict__ out) {
  out[blockIdx.x * NCLASS + threadIdx.x] =
      Z[(size_t)idx[blockIdx.x] * NCLASS + threadIdx.x];
}

// ---------------------------------------------------------------------------
// Launch
// ---------------------------------------------------------------------------
extern "C" void kernel_launch(void* const* d_in, const int* in_sizes, int n_in,
                              void* d_out, int out_size, void* d_ws, size_t ws_size,
                              hipStream_t stream) {
  const int*   u       = (const int*)  d_in[0];
  const int*   v       = (const int*)  d_in[1];
  const float* x       = (const float*)d_in[2];
  const int*   adj_row = (const int*)  d_in[3];
  const int*   adj_col = (const int*)  d_in[4];
  const float* adj_val = (const float*)d_in[5];
  const float* W1      = (const float*)d_in[6];
  const float* b1      = (const float*)d_in[7];
  const float* W2      = (const float*)d_in[8];
  const float* b2      = (const float*)d_in[9];
  const float* We      = (const float*)d_in[10];
  float* out = (float*)d_out;

  char* wsb = (char*)d_ws;
  // Region A [0, 51.2MB): S1; after spmm1 dead -> S2 [0,25.6) + Z [25.6,51.2)
  float* S1 = (float*)wsb;
  float* S2 = (float*)wsb;
  float* Z  = (float*)(wsb + (size_t)N_NODES * NCLASS * sizeof(float));
  // Region B [51.2MB, 102.4MB): Hhi/Hlo; after GEMM2 dead -> head scratch
  char* rB = wsb + (size_t)N_NODES * NHID * sizeof(float);
  unsigned short* Hhi = (unsigned short*)rB;
  unsigned short* Hlo = Hhi + (size_t)N_NODES * NHID;
  float* ZUG = (float*)rB;                 // 2048*128
  float* ZV  = ZUG + N_UV * NCLASS;        // 2048*128
  float* ZU  = ZV + N_UV * NCLASS;         // 2048*128
  // Split weights + row_ptr parked in d_out (dead until the final GEMM)
  unsigned short* W1Thi = (unsigned short*)out;
  unsigned short* W1Tlo = W1Thi + NHID * NFEAT;
  unsigned short* W2Thi = W1Tlo + NHID * NFEAT;
  unsigned short* W2Tlo = W2Thi + NCLASS * NHID;
  int* row_ptr = (int*)(W2Tlo + NCLASS * NHID);   // 50001 ints

  // 0) weight prep + row_ptr build
  split_transpose<<<(NFEAT * NHID + 255) / 256, 256, 0, stream>>>(W1, W1Thi, W1Tlo, NFEAT, NHID);
  split_transpose<<<(NHID * NCLASS + 255) / 256, 256, 0, stream>>>(W2, W2Thi, W2Tlo, NHID, NCLASS);
  build_row_ptr<<<(N_EDGES + 255) / 256, 256, 0, stream>>>(adj_row, row_ptr);

  // 1) S1 = x @ W1  (MFMA split-bf16, A split on the fly)
  gemm_mfma_split<true, false, false><<<dim3(NHID / 128, (N_NODES + 127) / 128), 256, 0, stream>>>(
      x, nullptr, nullptr, nullptr, W1Thi, W1Tlo, S1, N_NODES, NHID, NFEAT);

  // 2) Hhi/Hlo = split(relu(A @ S1 + b1))
  spmm256_split<<<N_NODES / 4, 256, 0, stream>>>(
      (const float4*)S1, row_ptr, adj_col, adj_val, (const float4*)b1, Hhi, Hlo);

  // 3) S2 = H @ W2  (MFMA split-bf16, A pre-split)
  gemm_mfma_split<false, false, false><<<dim3(NCLASS / 128, (N_NODES + 127) / 128), 256, 0, stream>>>(
      nullptr, Hhi, Hlo, nullptr, W2Thi, W2Tlo, S2, N_NODES, NCLASS, NHID);

  // 4) Z = A @ S2 + b2
  spmm128_f32<<<N_NODES / 4, 256, 0, stream>>>(
      (const float4*)S2, row_ptr, adj_col, adj_val, (const float4*)b2, (float4*)Z);

  // 5) head gathers: ZUG = Z[u], ZV = Z[v]
  gather_rows<<<N_UV, NCLASS, 0, stream>>>(Z, u, ZUG);
  gather_rows<<<N_UV, NCLASS, 0, stream>>>(Z, v, ZV);

  // 6) ZU = ZUG @ We^T   (BT = We as stored; both operands split on the fly)
  gemm_mfma_split<true, true, false><<<dim3(NCLASS / 128, N_UV / 128), 256, 0, stream>>>(
      ZUG, nullptr, nullptr, We, nullptr, nullptr, ZU, N_UV, NCLASS, NCLASS);

  // 7) out = sigmoid(ZU @ ZV^T)
  gemm_mfma_split<true, true, true><<<dim3(N_UV / 128, N_UV / 128), 256, 0, stream>>>(
      ZU, nullptr, nullptr, ZV, nullptr, nullptr, out, N_UV, N_UV, NCLASS);
}

// Round 7
// 422.003 us; speedup vs baseline: 1.5439x; 1.0183x over previous
//
#include <hip/hip_runtime.h>
#include <hip/hip_bf16.h>
#include <math.h>

// ---------------------------------------------------------------------------
// Problem constants (from reference)
// ---------------------------------------------------------------------------
#define N_NODES 50000
#define N_EDGES 800000
#define NFEAT   512
#define NHID    256
#define NCLASS  128
#define N_UV    2048

typedef __bf16    bf16x8 __attribute__((ext_vector_type(8)));
typedef short     s16x8  __attribute__((ext_vector_type(8)));
typedef float     f32x4  __attribute__((ext_vector_type(4)));

__device__ __forceinline__ unsigned short bf16_rn(float f) {
  unsigned u = __float_as_uint(f);
  u += 0x7fffu + ((u >> 16) & 1u);
  return (unsigned short)(u >> 16);
}
__device__ __forceinline__ float bf16_to_f(unsigned short h) {
  return __uint_as_float(((unsigned)h) << 16);
}

// ---------------------------------------------------------------------------
// Split-bf16 MFMA GEMM: C[M,N] = A[M,K] @ BT[N,K]^T  (fp32-quality via
// Ahi*Bhi + Ahi*Blo + Alo*Bhi). 128x128 tile, BK=32, 256 thr, 4 waves 2x2,
// each wave 4x4 tiles of mfma_f32_16x16x32_bf16.
// 2-stage register pipeline: prefetch tile k+1 into VGPRs during compute of
// tile k. launch_bounds(256,2): (256,4) spilled (round-4: WRITE 50->387MB).
// AIDX/BIDX: row indirection (fused gather) for the head GEMMs.
// ---------------------------------------------------------------------------
#define LDSPAD 40   // 32 + 8 shorts: keeps 16B alignment, breaks pow2 stride

template <bool ASPLIT, bool BSPLIT, bool SIGMOID, bool AIDX, bool BIDX>
__global__ __launch_bounds__(256, 2) void gemm_mfma_split(
    const float* __restrict__ Af,
    const unsigned short* __restrict__ Ahi, const unsigned short* __restrict__ Alo,
    const int* __restrict__ Aidx,
    const float* __restrict__ BTf,
    const unsigned short* __restrict__ BThi, const unsigned short* __restrict__ BTlo,
    const int* __restrict__ Bidx,
    float* __restrict__ C, int M, int N, int K) {
  __shared__ unsigned short sAh[128 * LDSPAD];
  __shared__ unsigned short sAl[128 * LDSPAD];
  __shared__ unsigned short sBh[128 * LDSPAD];
  __shared__ unsigned short sBl[128 * LDSPAD];

  const int tid  = threadIdx.x;
  const int lane = tid & 63;
  const int wave = tid >> 6;
  const int wm   = (wave >> 1) << 6;
  const int wn   = (wave & 1) << 6;
  const int lm   = lane & 15;
  const int quad = lane >> 4;
  const int m0   = blockIdx.y * 128;
  const int n0   = blockIdx.x * 128;

  const int r32 = tid >> 3;            // 0..31 (fp32 path: 32 rows/pass)
  const int c32 = (tid & 7) * 4;       // float4 col
  const int r16 = tid >> 2;            // 0..63 (bf16 path: 64 rows/pass)
  const int c16 = (tid & 3) * 8;       // s16x8 col

  float4 pA[4]; s16x8 pAh[2], pAl[2];
  float4 pB[4]; s16x8 pBh[2], pBl[2];

  f32x4 acc[4][4];
#pragma unroll
  for (int i = 0; i < 4; ++i)
#pragma unroll
    for (int j = 0; j < 4; ++j)
#pragma unroll
      for (int r = 0; r < 4; ++r) acc[i][j][r] = 0.f;

#define LOAD_TILE(k0)                                                          \
  do {                                                                         \
    if (ASPLIT) {                                                              \
      _Pragma("unroll") for (int p = 0; p < 4; ++p) {                          \
        const int m = m0 + p * 32 + r32;                                       \
        pA[p] = make_float4(0.f, 0.f, 0.f, 0.f);                               \
        if (m < M) {                                                           \
          const int ra = AIDX ? Aidx[m] : m;                                   \
          pA[p] = *(const float4*)&Af[(size_t)ra * K + (k0) + c32];            \
        }                                                                      \
      }                                                                        \
    } else {                                                                   \
      _Pragma("unroll") for (int p = 0; p < 2; ++p) {                          \
        const int m = m0 + p * 64 + r16;                                       \
        _Pragma("unroll") for (int e = 0; e < 8; ++e) { pAh[p][e] = 0; pAl[p][e] = 0; } \
        if (m < M) {                                                           \
          pAh[p] = *(const s16x8*)&Ahi[(size_t)m * K + (k0) + c16];            \
          pAl[p] = *(const s16x8*)&Alo[(size_t)m * K + (k0) + c16];            \
        }                                                                      \
      }                                                                        \
    }                                                                          \
    if (BSPLIT) {                                                              \
      _Pragma("unroll") for (int p = 0; p < 4; ++p) {                          \
        const int n = n0 + p * 32 + r32;                                       \
        const int rb = BIDX ? Bidx[n] : n;                                     \
        pB[p] = *(const float4*)&BTf[(size_t)rb * K + (k0) + c32];             \
      }                                                                        \
    } else {                                                                   \
      _Pragma("unroll") for (int p = 0; p < 2; ++p) {                          \
        pBh[p] = *(const s16x8*)&BThi[(size_t)(n0 + p * 64 + r16) * K + (k0) + c16]; \
        pBl[p] = *(const s16x8*)&BTlo[(size_t)(n0 + p * 64 + r16) * K + (k0) + c16]; \
      }                                                                        \
    }                                                                          \
  } while (0)

#define SPLIT4(v, hv, lv)                                                      \
  hv.x = bf16_rn(v.x); lv.x = bf16_rn(v.x - bf16_to_f(hv.x));                  \
  hv.y = bf16_rn(v.y); lv.y = bf16_rn(v.y - bf16_to_f(hv.y));                  \
  hv.z = bf16_rn(v.z); lv.z = bf16_rn(v.z - bf16_to_f(hv.z));                  \
  hv.w = bf16_rn(v.w); lv.w = bf16_rn(v.w - bf16_to_f(hv.w));

#define STORE_TILE()                                                           \
  do {                                                                         \
    if (ASPLIT) {                                                              \
      _Pragma("unroll") for (int p = 0; p < 4; ++p) {                          \
        ushort4 hv, lv; SPLIT4(pA[p], hv, lv);                                 \
        const int row = p * 32 + r32;                                          \
        *(ushort4*)&sAh[row * LDSPAD + c32] = hv;                              \
        *(ushort4*)&sAl[row * LDSPAD + c32] = lv;                              \
      }                                                                        \
    } else {                                                                   \
      _Pragma("unroll") for (int p = 0; p < 2; ++p) {                          \
        const int row = p * 64 + r16;                                          \
        *(s16x8*)&sAh[row * LDSPAD + c16] = pAh[p];                            \
        *(s16x8*)&sAl[row * LDSPAD + c16] = pAl[p];                            \
      }                                                                        \
    }                                                                          \
    if (BSPLIT) {                                                              \
      _Pragma("unroll") for (int p = 0; p < 4; ++p) {                          \
        ushort4 hv, lv; SPLIT4(pB[p], hv, lv);                                 \
        const int row = p * 32 + r32;                                          \
        *(ushort4*)&sBh[row * LDSPAD + c32] = hv;                              \
        *(ushort4*)&sBl[row * LDSPAD + c32] = lv;                              \
      }                                                                        \
    } else {                                                                   \
      _Pragma("unroll") for (int p = 0; p < 2; ++p) {                          \
        const int row = p * 64 + r16;                                          \
        *(s16x8*)&sBh[row * LDSPAD + c16] = pBh[p];                            \
        *(s16x8*)&sBl[row * LDSPAD + c16] = pBl[p];                            \
      }                                                                        \
    }                                                                          \
  } while (0)

  LOAD_TILE(0);

  for (int k0 = 0; k0 < K; k0 += 32) {
    if (k0) __syncthreads();      // WAR: prior iter's frag reads complete
    STORE_TILE();
    __syncthreads();              // RAW: stores visible
    if (k0 + 32 < K) LOAD_TILE(k0 + 32);   // prefetch next tile (latency hidden)

    bf16x8 aH[4], aL[4], bH[4], bL[4];
#pragma unroll
    for (int i = 0; i < 4; ++i) {
      const int r = wm + i * 16 + lm;
      aH[i] = __builtin_bit_cast(bf16x8, *(const s16x8*)&sAh[r * LDSPAD + quad * 8]);
      aL[i] = __builtin_bit_cast(bf16x8, *(const s16x8*)&sAl[r * LDSPAD + quad * 8]);
    }
#pragma unroll
    for (int j = 0; j < 4; ++j) {
      const int r = wn + j * 16 + lm;
      bH[j] = __builtin_bit_cast(bf16x8, *(const s16x8*)&sBh[r * LDSPAD + quad * 8]);
      bL[j] = __builtin_bit_cast(bf16x8, *(const s16x8*)&sBl[r * LDSPAD + quad * 8]);
    }
#pragma unroll
    for (int i = 0; i < 4; ++i)
#pragma unroll
      for (int j = 0; j < 4; ++j) {
        acc[i][j] = __builtin_amdgcn_mfma_f32_16x16x32_bf16(aH[i], bH[j], acc[i][j], 0, 0, 0);
        acc[i][j] = __builtin_amdgcn_mfma_f32_16x16x32_bf16(aH[i], bL[j], acc[i][j], 0, 0, 0);
        acc[i][j] = __builtin_amdgcn_mfma_f32_16x16x32_bf16(aL[i], bH[j], acc[i][j], 0, 0, 0);
      }
  }

  // ---- epilogue: C/D layout col=lane&15, row=quad*4+reg ----
#pragma unroll
  for (int i = 0; i < 4; ++i)
#pragma unroll
    for (int j = 0; j < 4; ++j) {
      const int col = n0 + wn + j * 16 + lm;
#pragma unroll
      for (int r = 0; r < 4; ++r) {
        const int row = m0 + wm + i * 16 + quad * 4 + r;
        if (row < M) {
          float v = acc[i][j][r];
          if (SIGMOID) v = 1.f / (1.f + expf(-v));
          C[(size_t)row * N + col] = v;
        }
      }
    }
#undef LOAD_TILE
#undef STORE_TILE
#undef SPLIT4
}

// ---------------------------------------------------------------------------
// Fused prep: row_ptr build (edge-parallel) + W1/W2 transpose+split.
// ---------------------------------------------------------------------------
__global__ __launch_bounds__(256) void prep_all(
    const int* __restrict__ rows, int* __restrict__ row_ptr,
    const float* __restrict__ W1, unsigned short* __restrict__ W1Thi,
    unsigned short* __restrict__ W1Tlo,
    const float* __restrict__ W2, unsigned short* __restrict__ W2Thi,
    unsigned short* __restrict__ W2Tlo) {
  const int idx = blockIdx.x * 256 + threadIdx.x;
  if (idx < N_EDGES) {
    const int r = rows[idx];
    const int rprev = (idx == 0) ? -1 : rows[idx - 1];
    for (int n = rprev + 1; n <= r; ++n) row_ptr[n] = idx;
    if (idx == N_EDGES - 1)
      for (int n = r + 1; n <= N_NODES; ++n) row_ptr[n] = N_EDGES;
  }
  if (idx < NFEAT * NHID) {   // W1T[n*K+k] = split(W1[k*N+n]), K=NFEAT N=NHID
    const int n = idx / NFEAT;
    const int k = idx - n * NFEAT;
    const float f = W1[(size_t)k * NHID + n];
    const unsigned short h = bf16_rn(f);
    W1Thi[idx] = h;
    W1Tlo[idx] = bf16_rn(f - bf16_to_f(h));
  }
  if (idx < NHID * NCLASS) {  // W2T, K=NHID N=NCLASS
    const int n = idx / NHID;
    const int k = idx - n * NHID;
    const float f = W2[(size_t)k * NCLASS + n];
    const unsigned short h = bf16_rn(f);
    W2Thi[idx] = h;
    W2Tlo[idx] = bf16_rn(f - bf16_to_f(h));
  }
}

// ---------------------------------------------------------------------------
// SpMM F=256 fp32: one wave per node, lane covers 4 feats (float4 = full
// 1KB row per wave), 8-edge unroll (128 B/lane outstanding -> MLP).
// Fused bias+relu+bf16 hi/lo split output.
// ---------------------------------------------------------------------------
__global__ __launch_bounds__(256) void spmm256_split(
    const float4* __restrict__ S4, const int* __restrict__ row_ptr,
    const int* __restrict__ cols, const float* __restrict__ vals,
    const float4* __restrict__ bias4,
    unsigned short* __restrict__ outHi, unsigned short* __restrict__ outLo) {
  const int wave = threadIdx.x >> 6;
  const int lane = threadIdx.x & 63;
  const int node = blockIdx.x * 4 + wave;

  const int lo = row_ptr[node];
  const int hi = row_ptr[node + 1];

  float4 acc = make_float4(0.f, 0.f, 0.f, 0.f);
  int e = lo;
  for (; e + 8 <= hi; e += 8) {
    int c[8]; float w[8];
#pragma unroll
    for (int t = 0; t < 8; ++t) { c[t] = cols[e + t]; w[t] = vals[e + t]; }
    float4 r[8];
#pragma unroll
    for (int t = 0; t < 8; ++t) r[t] = S4[(size_t)c[t] * 64 + lane];
#pragma unroll
    for (int t = 0; t < 8; ++t) {
      acc.x = fmaf(w[t], r[t].x, acc.x); acc.y = fmaf(w[t], r[t].y, acc.y);
      acc.z = fmaf(w[t], r[t].z, acc.z); acc.w = fmaf(w[t], r[t].w, acc.w);
    }
  }
  for (; e < hi; ++e) {
    const int c = cols[e];
    const float w = vals[e];
    const float4 r = S4[(size_t)c * 64 + lane];
    acc.x = fmaf(w, r.x, acc.x); acc.y = fmaf(w, r.y, acc.y);
    acc.z = fmaf(w, r.z, acc.z); acc.w = fmaf(w, r.w, acc.w);
  }

  const float4 b = bias4[lane];
  acc.x = fmaxf(acc.x + b.x, 0.f);
  acc.y = fmaxf(acc.y + b.y, 0.f);
  acc.z = fmaxf(acc.z + b.z, 0.f);
  acc.w = fmaxf(acc.w + b.w, 0.f);

  ushort4 hv, lv;
  hv.x = bf16_rn(acc.x); lv.x = bf16_rn(acc.x - bf16_to_f(hv.x));
  hv.y = bf16_rn(acc.y); lv.y = bf16_rn(acc.y - bf16_to_f(hv.y));
  hv.z = bf16_rn(acc.z); lv.z = bf16_rn(acc.z - bf16_to_f(hv.z));
  hv.w = bf16_rn(acc.w); lv.w = bf16_rn(acc.w - bf16_to_f(hv.w));
  const size_t o = (size_t)node * NHID + lane * 4;
  *(ushort4*)&outHi[o] = hv;
  *(ushort4*)&outLo[o] = lv;
}

// ---------------------------------------------------------------------------
// SpMM F=128 fp32: one wave per node; half-waves process alternating edges
// with float4 (full 512B row per half), 4-edge unroll per half (8 edges in
// flight per wave), shfl_xor combine. fp32 out.
// ---------------------------------------------------------------------------
__global__ __launch_bounds__(256) void spmm128_f32(
    const float4* __restrict__ S4, const int* __restrict__ row_ptr,
    const int* __restrict__ cols, const float* __restrict__ vals,
    const float4* __restrict__ bias4, float4* __restrict__ out4) {
  const int wave = threadIdx.x >> 6;
  const int lane = threadIdx.x & 63;
  const int half = lane >> 5;
  const int l32  = lane & 31;
  const int node = blockIdx.x * 4 + wave;

  const int lo = row_ptr[node];
  const int hi = row_ptr[node + 1];

  float4 acc = make_float4(0.f, 0.f, 0.f, 0.f);
  int e = lo + half;
  for (; e + 6 < hi; e += 8) {   // edges e, e+2, e+4, e+6 for this half
    int c[4]; float w[4];
#pragma unroll
    for (int t = 0; t < 4; ++t) { c[t] = cols[e + 2 * t]; w[t] = vals[e + 2 * t]; }
    float4 r[4];
#pragma unroll
    for (int t = 0; t < 4; ++t) r[t] = S4[(size_t)c[t] * 32 + l32];
#pragma unroll
    for (int t = 0; t < 4; ++t) {
      acc.x = fmaf(w[t], r[t].x, acc.x); acc.y = fmaf(w[t], r[t].y, acc.y);
      acc.z = fmaf(w[t], r[t].z, acc.z); acc.w = fmaf(w[t], r[t].w, acc.w);
    }
  }
  for (; e < hi; e += 2) {
    const int c = cols[e];
    const float w = vals[e];
    const float4 r = S4[(size_t)c * 32 + l32];
    acc.x = fmaf(w, r.x, acc.x); acc.y = fmaf(w, r.y, acc.y);
    acc.z = fmaf(w, r.z, acc.z); acc.w = fmaf(w, r.w, acc.w);
  }

  acc.x += __shfl_xor(acc.x, 32);
  acc.y += __shfl_xor(acc.y, 32);
  acc.z += __shfl_xor(acc.z, 32);
  acc.w += __shfl_xor(acc.w, 32);

  if (half == 0) {
    const float4 b = bias4[l32];
    acc.x += b.x; acc.y += b.y; acc.z += b.z; acc.w += b.w;
    out4[(size_t)node * 32 + l32] = acc;
  }
}

// ---------------------------------------------------------------------------
// Launch
// ---------------------------------------------------------------------------
extern "C" void kernel_launch(void* const* d_in, const int* in_sizes, int n_in,
                              void* d_out, int out_size, void* d_ws, size_t ws_size,
                              hipStream_t stream) {
  const int*   u       = (const int*)  d_in[0];
  const int*   v       = (const int*)  d_in[1];
  const float* x       = (const float*)d_in[2];
  const int*   adj_row = (const int*)  d_in[3];
  const int*   adj_col = (const int*)  d_in[4];
  const float* adj_val = (const float*)d_in[5];
  const float* W1      = (const float*)d_in[6];
  const float* b1      = (const float*)d_in[7];
  const float* W2      = (const float*)d_in[8];
  const float* b2      = (const float*)d_in[9];
  const float* We      = (const float*)d_in[10];
  float* out = (float*)d_out;

  char* wsb = (char*)d_ws;
  // Region A [0, 51.2MB): S1; after spmm1 dead -> S2 [0,25.6) + Z [25.6,51.2)
  float* S1 = (float*)wsb;
  float* S2 = (float*)wsb;
  float* Z  = (float*)(wsb + (size_t)N_NODES * NCLASS * sizeof(float));
  // Region B [51.2MB, 102.4MB): Hhi/Hlo; after GEMM2 dead -> ZU
  char* rB = wsb + (size_t)N_NODES * NHID * sizeof(float);
  unsigned short* Hhi = (unsigned short*)rB;
  unsigned short* Hlo = Hhi + (size_t)N_NODES * NHID;
  float* ZU = (float*)rB;                  // 2048*128
  // Split weights + row_ptr parked in d_out (dead until the final GEMM)
  unsigned short* W1Thi = (unsigned short*)out;
  unsigned short* W1Tlo = W1Thi + NHID * NFEAT;
  unsigned short* W2Thi = W1Tlo + NHID * NFEAT;
  unsigned short* W2Tlo = W2Thi + NCLASS * NHID;
  int* row_ptr = (int*)(W2Tlo + NCLASS * NHID);   // 50001 ints

  // 0) fused prep: row_ptr + weight transpose/split (one launch)
  prep_all<<<(N_EDGES + 255) / 256, 256, 0, stream>>>(
      adj_row, row_ptr, W1, W1Thi, W1Tlo, W2, W2Thi, W2Tlo);

  // 1) S1 = x @ W1  (MFMA split-bf16, A split on the fly)
  gemm_mfma_split<true, false, false, false, false>
      <<<dim3(NHID / 128, (N_NODES + 127) / 128), 256, 0, stream>>>(
      x, nullptr, nullptr, nullptr, nullptr, W1Thi, W1Tlo, nullptr,
      S1, N_NODES, NHID, NFEAT);

  // 2) Hhi/Hlo = split(relu(A @ S1 + b1))   (fp32 gather, 8-deep MLP)
  spmm256_split<<<N_NODES / 4, 256, 0, stream>>>(
      (const float4*)S1, row_ptr, adj_col, adj_val, (const float4*)b1, Hhi, Hlo);

  // 3) S2 = H @ W2  (MFMA split-bf16, A pre-split)
  gemm_mfma_split<false, false, false, false, false>
      <<<dim3(NCLASS / 128, (N_NODES + 127) / 128), 256, 0, stream>>>(
      nullptr, Hhi, Hlo, nullptr, nullptr, W2Thi, W2Tlo, nullptr,
      S2, N_NODES, NCLASS, NHID);

  // 4) Z = A @ S2 + b2   (fp32 gather, 8-deep MLP)
  spmm128_f32<<<N_NODES / 4, 256, 0, stream>>>(
      (const float4*)S2, row_ptr, adj_col, adj_val, (const float4*)b2, (float4*)Z);

  // 5) ZU = Z[u] @ We^T  (fused gather via AIDX; BT = We as stored)
  gemm_mfma_split<true, true, false, true, false>
      <<<dim3(NCLASS / 128, N_UV / 128), 256, 0, stream>>>(
      Z, nullptr, nullptr, u, We, nullptr, nullptr, nullptr,
      ZU, N_UV, NCLASS, NCLASS);

  // 6) out = sigmoid(ZU @ Z[v]^T)  (fused gather via BIDX)
  gemm_mfma_split<true, true, true, false, true>
      <<<dim3(N_UV / 128, N_UV / 128), 256, 0, stream>>>(
      ZU, nullptr, nullptr, nullptr, Z, nullptr, nullptr, v,
      out, N_UV, N_UV, NCLASS);
}

// Round 8
// 398.929 us; speedup vs baseline: 1.6332x; 1.0578x over previous
//
#include <hip/hip_runtime.h>
#include <hip/hip_bf16.h>
#include <math.h>

// ---------------------------------------------------------------------------
// Problem constants (from reference)
// ---------------------------------------------------------------------------
#define N_NODES 50000
#define N_EDGES 800000
#define NFEAT   512
#define NHID    256
#define NCLASS  128
#define N_UV    2048

// q24 fixed-point: scale 2^19, range +-16 (|S1|<~6, |S2|<~4 -> wide margin)
#define Q24_SCALE  524288.0f
#define Q24_INV    1.9073486328125e-6f

typedef __bf16    bf16x8 __attribute__((ext_vector_type(8)));
typedef short     s16x8  __attribute__((ext_vector_type(8)));
typedef float     f32x4  __attribute__((ext_vector_type(4)));

struct __attribute__((packed)) U3 { unsigned a, b, c; };  // 12B dwordx3 view

__device__ __forceinline__ unsigned short bf16_rn(float f) {
  unsigned u = __float_as_uint(f);
  u += 0x7fffu + ((u >> 16) & 1u);
  return (unsigned short)(u >> 16);
}
__device__ __forceinline__ float bf16_to_f(unsigned short h) {
  return __uint_as_float(((unsigned)h) << 16);
}
// 4 x 24-bit signed little-endian values from 3 dwords
__device__ __forceinline__ void unpack24(unsigned a, unsigned b, unsigned c,
                                         int& e0, int& e1, int& e2, int& e3) {
  e0 = ((int)(a << 8)) >> 8;
  e1 = ((int)((b << 16) | ((a >> 24) << 8))) >> 8;
  e2 = ((int)((c << 24) | ((b >> 16) << 8))) >> 8;
  e3 = ((int)c) >> 8;
}
__device__ __forceinline__ void pack24(float v, unsigned char* p) {
  int q = __float2int_rn(v * Q24_SCALE);
  q = q > 8388607 ? 8388607 : (q < -8388608 ? -8388608 : q);
  p[0] = (unsigned char)(q & 0xFF);
  p[1] = (unsigned char)((q >> 8) & 0xFF);
  p[2] = (unsigned char)((q >> 16) & 0xFF);
}

// ---------------------------------------------------------------------------
// Split-bf16 MFMA GEMM: C[M,N] = A[M,K] @ BT[N,K]^T  (fp32-quality via
// Ahi*Bhi + Ahi*Blo + Alo*Bhi). 128x128 tile, BK=32, 256 thr, 4 waves 2x2,
// each wave 4x4 tiles of mfma_f32_16x16x32_bf16.
// 2-stage register pipeline: prefetch tile k+1 into VGPRs during compute of
// tile k. launch_bounds(256,2): (256,4) spilled (round-4: WRITE 50->387MB).
// AIDX/BIDX: row indirection (fused gather) for the head GEMMs.
// OMODE: 0 = fp32 C, 1 = sigmoid fp32 C, 2 = q24 packed (3B/elem) to Cq.
// ---------------------------------------------------------------------------
#define LDSPAD 40   // 32 + 8 shorts: keeps 16B alignment, breaks pow2 stride

template <bool ASPLIT, bool BSPLIT, int OMODE, bool AIDX, bool BIDX>
__global__ __launch_bounds__(256, 2) void gemm_mfma_split(
    const float* __restrict__ Af,
    const unsigned short* __restrict__ Ahi, const unsigned short* __restrict__ Alo,
    const int* __restrict__ Aidx,
    const float* __restrict__ BTf,
    const unsigned short* __restrict__ BThi, const unsigned short* __restrict__ BTlo,
    const int* __restrict__ Bidx,
    float* __restrict__ C, unsigned char* __restrict__ Cq, int M, int N, int K) {
  __shared__ unsigned short sAh[128 * LDSPAD];
  __shared__ unsigned short sAl[128 * LDSPAD];
  __shared__ unsigned short sBh[128 * LDSPAD];
  __shared__ unsigned short sBl[128 * LDSPAD];

  const int tid  = threadIdx.x;
  const int lane = tid & 63;
  const int wave = tid >> 6;
  const int wm   = (wave >> 1) << 6;
  const int wn   = (wave & 1) << 6;
  const int lm   = lane & 15;
  const int quad = lane >> 4;
  const int m0   = blockIdx.y * 128;
  const int n0   = blockIdx.x * 128;

  const int r32 = tid >> 3;            // 0..31 (fp32 path: 32 rows/pass)
  const int c32 = (tid & 7) * 4;       // float4 col
  const int r16 = tid >> 2;            // 0..63 (bf16 path: 64 rows/pass)
  const int c16 = (tid & 3) * 8;       // s16x8 col

  float4 pA[4]; s16x8 pAh[2], pAl[2];
  float4 pB[4]; s16x8 pBh[2], pBl[2];

  f32x4 acc[4][4];
#pragma unroll
  for (int i = 0; i < 4; ++i)
#pragma unroll
    for (int j = 0; j < 4; ++j)
#pragma unroll
      for (int r = 0; r < 4; ++r) acc[i][j][r] = 0.f;

#define LOAD_TILE(k0)                                                          \
  do {                                                                         \
    if (ASPLIT) {                                                              \
      _Pragma("unroll") for (int p = 0; p < 4; ++p) {                          \
        const int m = m0 + p * 32 + r32;                                       \
        pA[p] = make_float4(0.f, 0.f, 0.f, 0.f);                               \
        if (m < M) {                                                           \
          const int ra = AIDX ? Aidx[m] : m;                                   \
          pA[p] = *(const float4*)&Af[(size_t)ra * K + (k0) + c32];            \
        }                                                                      \
      }                                                                        \
    } else {                                                                   \
      _Pragma("unroll") for (int p = 0; p < 2; ++p) {                          \
        const int m = m0 + p * 64 + r16;                                       \
        _Pragma("unroll") for (int e = 0; e < 8; ++e) { pAh[p][e] = 0; pAl[p][e] = 0; } \
        if (m < M) {                                                           \
          pAh[p] = *(const s16x8*)&Ahi[(size_t)m * K + (k0) + c16];            \
          pAl[p] = *(const s16x8*)&Alo[(size_t)m * K + (k0) + c16];            \
        }                                                                      \
      }                                                                        \
    }                                                                          \
    if (BSPLIT) {                                                              \
      _Pragma("unroll") for (int p = 0; p < 4; ++p) {                          \
        const int n = n0 + p * 32 + r32;                                       \
        const int rb = BIDX ? Bidx[n] : n;                                     \
        pB[p] = *(const float4*)&BTf[(size_t)rb * K + (k0) + c32];             \
      }                                                                        \
    } else {                                                                   \
      _Pragma("unroll") for (int p = 0; p < 2; ++p) {                          \
        pBh[p] = *(const s16x8*)&BThi[(size_t)(n0 + p * 64 + r16) * K + (k0) + c16]; \
        pBl[p] = *(const s16x8*)&BTlo[(size_t)(n0 + p * 64 + r16) * K + (k0) + c16]; \
      }                                                                        \
    }                                                                          \
  } while (0)

#define SPLIT4(v, hv, lv)                                                      \
  hv.x = bf16_rn(v.x); lv.x = bf16_rn(v.x - bf16_to_f(hv.x));                  \
  hv.y = bf16_rn(v.y); lv.y = bf16_rn(v.y - bf16_to_f(hv.y));                  \
  hv.z = bf16_rn(v.z); lv.z = bf16_rn(v.z - bf16_to_f(hv.z));                  \
  hv.w = bf16_rn(v.w); lv.w = bf16_rn(v.w - bf16_to_f(hv.w));

#define STORE_TILE()                                                           \
  do {                                                                         \
    if (ASPLIT) {                                                              \
      _Pragma("unroll") for (int p = 0; p < 4; ++p) {                          \
        ushort4 hv, lv; SPLIT4(pA[p], hv, lv);                                 \
        const int row = p * 32 + r32;                                          \
        *(ushort4*)&sAh[row * LDSPAD + c32] = hv;                              \
        *(ushort4*)&sAl[row * LDSPAD + c32] = lv;                              \
      }                                                                        \
    } else {                                                                   \
      _Pragma("unroll") for (int p = 0; p < 2; ++p) {                          \
        const int row = p * 64 + r16;                                          \
        *(s16x8*)&sAh[row * LDSPAD + c16] = pAh[p];                            \
        *(s16x8*)&sAl[row * LDSPAD + c16] = pAl[p];                            \
      }                                                                        \
    }                                                                          \
    if (BSPLIT) {                                                              \
      _Pragma("unroll") for (int p = 0; p < 4; ++p) {                          \
        ushort4 hv, lv; SPLIT4(pB[p], hv, lv);                                 \
        const int row = p * 32 + r32;                                          \
        *(ushort4*)&sBh[row * LDSPAD + c32] = hv;                              \
        *(ushort4*)&sBl[row * LDSPAD + c32] = lv;                              \
      }                                                                        \
    } else {                                                                   \
      _Pragma("unroll") for (int p = 0; p < 2; ++p) {                          \
        const int row = p * 64 + r16;                                          \
        *(s16x8*)&sBh[row * LDSPAD + c16] = pBh[p];                            \
        *(s16x8*)&sBl[row * LDSPAD + c16] = pBl[p];                            \
      }                                                                        \
    }                                                                          \
  } while (0)

  LOAD_TILE(0);

  for (int k0 = 0; k0 < K; k0 += 32) {
    if (k0) __syncthreads();      // WAR: prior iter's frag reads complete
    STORE_TILE();
    __syncthreads();              // RAW: stores visible
    if (k0 + 32 < K) LOAD_TILE(k0 + 32);   // prefetch next tile (latency hidden)

    bf16x8 aH[4], aL[4], bH[4], bL[4];
#pragma unroll
    for (int i = 0; i < 4; ++i) {
      const int r = wm + i * 16 + lm;
      aH[i] = __builtin_bit_cast(bf16x8, *(const s16x8*)&sAh[r * LDSPAD + quad * 8]);
      aL[i] = __builtin_bit_cast(bf16x8, *(const s16x8*)&sAl[r * LDSPAD + quad * 8]);
    }
#pragma unroll
    for (int j = 0; j < 4; ++j) {
      const int r = wn + j * 16 + lm;
      bH[j] = __builtin_bit_cast(bf16x8, *(const s16x8*)&sBh[r * LDSPAD + quad * 8]);
      bL[j] = __builtin_bit_cast(bf16x8, *(const s16x8*)&sBl[r * LDSPAD + quad * 8]);
    }
#pragma unroll
    for (int i = 0; i < 4; ++i)
#pragma unroll
      for (int j = 0; j < 4; ++j) {
        acc[i][j] = __builtin_amdgcn_mfma_f32_16x16x32_bf16(aH[i], bH[j], acc[i][j], 0, 0, 0);
        acc[i][j] = __builtin_amdgcn_mfma_f32_16x16x32_bf16(aH[i], bL[j], acc[i][j], 0, 0, 0);
        acc[i][j] = __builtin_amdgcn_mfma_f32_16x16x32_bf16(aL[i], bH[j], acc[i][j], 0, 0, 0);
      }
  }

  // ---- epilogue: C/D layout col=lane&15, row=quad*4+reg ----
#pragma unroll
  for (int i = 0; i < 4; ++i)
#pragma unroll
    for (int j = 0; j < 4; ++j) {
      const int col = n0 + wn + j * 16 + lm;
#pragma unroll
      for (int r = 0; r < 4; ++r) {
        const int row = m0 + wm + i * 16 + quad * 4 + r;
        if (row < M) {
          float v = acc[i][j][r];
          if (OMODE == 1) {
            v = 1.f / (1.f + expf(-v));
            C[(size_t)row * N + col] = v;
          } else if (OMODE == 2) {
            pack24(v, Cq + ((size_t)row * N + col) * 3);
          } else {
            C[(size_t)row * N + col] = v;
          }
        }
      }
    }
#undef LOAD_TILE
#undef STORE_TILE
#undef SPLIT4
}

// ---------------------------------------------------------------------------
// Fused prep: row_ptr build (edge-parallel) + W1/W2 transpose+split.
// ---------------------------------------------------------------------------
__global__ __launch_bounds__(256) void prep_all(
    const int* __restrict__ rows, int* __restrict__ row_ptr,
    const float* __restrict__ W1, unsigned short* __restrict__ W1Thi,
    unsigned short* __restrict__ W1Tlo,
    const float* __restrict__ W2, unsigned short* __restrict__ W2Thi,
    unsigned short* __restrict__ W2Tlo) {
  const int idx = blockIdx.x * 256 + threadIdx.x;
  if (idx < N_EDGES) {
    const int r = rows[idx];
    const int rprev = (idx == 0) ? -1 : rows[idx - 1];
    for (int n = rprev + 1; n <= r; ++n) row_ptr[n] = idx;
    if (idx == N_EDGES - 1)
      for (int n = r + 1; n <= N_NODES; ++n) row_ptr[n] = N_EDGES;
  }
  if (idx < NFEAT * NHID) {   // W1T[n*K+k] = split(W1[k*N+n]), K=NFEAT N=NHID
    const int n = idx / NFEAT;
    const int k = idx - n * NFEAT;
    const float f = W1[(size_t)k * NHID + n];
    const unsigned short h = bf16_rn(f);
    W1Thi[idx] = h;
    W1Tlo[idx] = bf16_rn(f - bf16_to_f(h));
  }
  if (idx < NHID * NCLASS) {  // W2T, K=NHID N=NCLASS
    const int n = idx / NHID;
    const int k = idx - n * NHID;
    const float f = W2[(size_t)k * NCLASS + n];
    const unsigned short h = bf16_rn(f);
    W2Thi[idx] = h;
    W2Tlo[idx] = bf16_rn(f - bf16_to_f(h));
  }
}

// ---------------------------------------------------------------------------
// SpMM F=256, q24 source (768B rows): one wave per node, lane = 12B dwordx3
// = 4 elems (full row per wave), 8-edge unroll. fp32 accumulate.
// Fused bias+relu+bf16 hi/lo split output.
// ---------------------------------------------------------------------------
__global__ __launch_bounds__(256) void spmm256_q24_split(
    const unsigned char* __restrict__ Sq, const int* __restrict__ row_ptr,
    const int* __restrict__ cols, const float* __restrict__ vals,
    const float4* __restrict__ bias4,
    unsigned short* __restrict__ outHi, unsigned short* __restrict__ outLo) {
  const int wave = threadIdx.x >> 6;
  const int lane = threadIdx.x & 63;
  const int node = blockIdx.x * 4 + wave;

  const int lo = row_ptr[node];
  const int hi = row_ptr[node + 1];

  float4 acc = make_float4(0.f, 0.f, 0.f, 0.f);

#define ACCQ(dd, ww)                                                           \
  do {                                                                         \
    int e0, e1, e2, e3;                                                        \
    unpack24((dd).a, (dd).b, (dd).c, e0, e1, e2, e3);                          \
    const float ws = (ww) * Q24_INV;                                           \
    acc.x = fmaf(ws, (float)e0, acc.x);                                        \
    acc.y = fmaf(ws, (float)e1, acc.y);                                        \
    acc.z = fmaf(ws, (float)e2, acc.z);                                        \
    acc.w = fmaf(ws, (float)e3, acc.w);                                        \
  } while (0)

  int e = lo;
  for (; e + 8 <= hi; e += 8) {
    int c[8]; float w[8];
#pragma unroll
    for (int t = 0; t < 8; ++t) { c[t] = cols[e + t]; w[t] = vals[e + t]; }
    U3 d[8];
#pragma unroll
    for (int t = 0; t < 8; ++t)
      d[t] = *(const U3*)&Sq[(size_t)c[t] * (NHID * 3) + lane * 12];
#pragma unroll
    for (int t = 0; t < 8; ++t) ACCQ(d[t], w[t]);
  }
  for (; e < hi; ++e) {
    const U3 d = *(const U3*)&Sq[(size_t)cols[e] * (NHID * 3) + lane * 12];
    ACCQ(d, vals[e]);
  }
#undef ACCQ

  const float4 b = bias4[lane];
  acc.x = fmaxf(acc.x + b.x, 0.f);
  acc.y = fmaxf(acc.y + b.y, 0.f);
  acc.z = fmaxf(acc.z + b.z, 0.f);
  acc.w = fmaxf(acc.w + b.w, 0.f);

  ushort4 hv, lv;
  hv.x = bf16_rn(acc.x); lv.x = bf16_rn(acc.x - bf16_to_f(hv.x));
  hv.y = bf16_rn(acc.y); lv.y = bf16_rn(acc.y - bf16_to_f(hv.y));
  hv.z = bf16_rn(acc.z); lv.z = bf16_rn(acc.z - bf16_to_f(hv.z));
  hv.w = bf16_rn(acc.w); lv.w = bf16_rn(acc.w - bf16_to_f(hv.w));
  const size_t o = (size_t)node * NHID + lane * 4;
  *(ushort4*)&outHi[o] = hv;
  *(ushort4*)&outLo[o] = lv;
}

// ---------------------------------------------------------------------------
// SpMM F=128, q24 source (384B rows): one wave per node; half-waves take
// alternating edges (32 lanes x 12B = full row), 4-edge unroll per half,
// shfl_xor combine. fp32 bias + output Z (feeds head GEMMs).
// ---------------------------------------------------------------------------
__global__ __launch_bounds__(256) void spmm128_q24(
    const unsigned char* __restrict__ Sq, const int* __restrict__ row_ptr,
    const int* __restrict__ cols, const float* __restrict__ vals,
    const float* __restrict__ bias, float* __restrict__ Z) {
  const int wave = threadIdx.x >> 6;
  const int lane = threadIdx.x & 63;
  const int half = lane >> 5;
  const int l32  = lane & 31;
  const int node = blockIdx.x * 4 + wave;

  const int lo = row_ptr[node];
  const int hi = row_ptr[node + 1];

  float acc[4] = {0.f, 0.f, 0.f, 0.f};

#define ACCQ(dd, ww)                                                           \
  do {                                                                         \
    int e0, e1, e2, e3;                                                        \
    unpack24((dd).a, (dd).b, (dd).c, e0, e1, e2, e3);                          \
    const float ws = (ww) * Q24_INV;                                           \
    acc[0] = fmaf(ws, (float)e0, acc[0]);                                      \
    acc[1] = fmaf(ws, (float)e1, acc[1]);                                      \
    acc[2] = fmaf(ws, (float)e2, acc[2]);                                      \
    acc[3] = fmaf(ws, (float)e3, acc[3]);                                      \
  } while (0)

  int e = lo + half;
  for (; e + 6 < hi; e += 8) {   // edges e, e+2, e+4, e+6 for this half
    int c[4]; float w[4];
#pragma unroll
    for (int t = 0; t < 4; ++t) { c[t] = cols[e + 2 * t]; w[t] = vals[e + 2 * t]; }
    U3 d[4];
#pragma unroll
    for (int t = 0; t < 4; ++t)
      d[t] = *(const U3*)&Sq[(size_t)c[t] * (NCLASS * 3) + l32 * 12];
#pragma unroll
    for (int t = 0; t < 4; ++t) ACCQ(d[t], w[t]);
  }
  for (; e < hi; e += 2) {
    const U3 d = *(const U3*)&Sq[(size_t)cols[e] * (NCLASS * 3) + l32 * 12];
    ACCQ(d, vals[e]);
  }
#undef ACCQ

#pragma unroll
  for (int k = 0; k < 4; ++k) acc[k] += __shfl_xor(acc[k], 32);

  if (half == 0) {
    float4 v;
    v.x = acc[0] + bias[l32 * 4 + 0];
    v.y = acc[1] + bias[l32 * 4 + 1];
    v.z = acc[2] + bias[l32 * 4 + 2];
    v.w = acc[3] + bias[l32 * 4 + 3];
    *(float4*)&Z[(size_t)node * NCLASS + l32 * 4] = v;
  }
}

// ---------------------------------------------------------------------------
// Launch
// ---------------------------------------------------------------------------
extern "C" void kernel_launch(void* const* d_in, const int* in_sizes, int n_in,
                              void* d_out, int out_size, void* d_ws, size_t ws_size,
                              hipStream_t stream) {
  const int*   u       = (const int*)  d_in[0];
  const int*   v       = (const int*)  d_in[1];
  const float* x       = (const float*)d_in[2];
  const int*   adj_row = (const int*)  d_in[3];
  const int*   adj_col = (const int*)  d_in[4];
  const float* adj_val = (const float*)d_in[5];
  const float* W1      = (const float*)d_in[6];
  const float* b1      = (const float*)d_in[7];
  const float* W2      = (const float*)d_in[8];
  const float* b2      = (const float*)d_in[9];
  const float* We      = (const float*)d_in[10];
  float* out = (float*)d_out;

  char* wsb = (char*)d_ws;
  // Region A [0, 51.2MB):
  //   S1q q24 [0, 38.4MB); after spmm1 -> S2q q24 [0, 19.2MB), Z [19.2, 44.8)
  unsigned char* S1q = (unsigned char*)wsb;
  unsigned char* S2q = (unsigned char*)wsb;
  float* Z = (float*)(wsb + (size_t)N_NODES * NCLASS * 3);   // 19.2MB offset
  // Region B [51.2MB, 102.4MB): Hhi/Hlo; after GEMM2 dead -> ZU
  char* rB = wsb + (size_t)N_NODES * NHID * sizeof(float);
  unsigned short* Hhi = (unsigned short*)rB;
  unsigned short* Hlo = Hhi + (size_t)N_NODES * NHID;
  float* ZU = (float*)rB;                  // 2048*128
  // Split weights + row_ptr parked in d_out (dead until the final GEMM)
  unsigned short* W1Thi = (unsigned short*)out;
  unsigned short* W1Tlo = W1Thi + NHID * NFEAT;
  unsigned short* W2Thi = W1Tlo + NHID * NFEAT;
  unsigned short* W2Tlo = W2Thi + NCLASS * NHID;
  int* row_ptr = (int*)(W2Tlo + NCLASS * NHID);   // 50001 ints

  // 0) fused prep: row_ptr + weight transpose/split (one launch)
  prep_all<<<(N_EDGES + 255) / 256, 256, 0, stream>>>(
      adj_row, row_ptr, W1, W1Thi, W1Tlo, W2, W2Thi, W2Tlo);

  // 1) S1q = q24(x @ W1)  (MFMA split-bf16, A split on the fly)
  gemm_mfma_split<true, false, 2, false, false>
      <<<dim3(NHID / 128, (N_NODES + 127) / 128), 256, 0, stream>>>(
      x, nullptr, nullptr, nullptr, nullptr, W1Thi, W1Tlo, nullptr,
      nullptr, S1q, N_NODES, NHID, NFEAT);

  // 2) Hhi/Hlo = split(relu(A @ S1 + b1))   (q24 gather: 768B rows)
  spmm256_q24_split<<<N_NODES / 4, 256, 0, stream>>>(
      S1q, row_ptr, adj_col, adj_val, (const float4*)b1, Hhi, Hlo);

  // 3) S2q = q24(H @ W2)  (MFMA split-bf16, A pre-split)
  gemm_mfma_split<false, false, 2, false, false>
      <<<dim3(NCLASS / 128, (N_NODES + 127) / 128), 256, 0, stream>>>(
      nullptr, Hhi, Hlo, nullptr, nullptr, W2Thi, W2Tlo, nullptr,
      nullptr, S2q, N_NODES, NCLASS, NHID);

  // 4) Z = A @ S2 + b2   (q24 gather: 384B rows)
  spmm128_q24<<<N_NODES / 4, 256, 0, stream>>>(
      S2q, row_ptr, adj_col, adj_val, b2, Z);

  // 5) ZU = Z[u] @ We^T  (fused gather via AIDX; BT = We as stored)
  gemm_mfma_split<true, true, 0, true, false>
      <<<dim3(NCLASS / 128, N_UV / 128), 256, 0, stream>>>(
      Z, nullptr, nullptr, u, We, nullptr, nullptr, nullptr,
      ZU, nullptr, N_UV, NCLASS, NCLASS);

  // 6) out = sigmoid(ZU @ Z[v]^T)  (fused gather via BIDX)
  gemm_mfma_split<true, true, 1, false, true>
      <<<dim3(N_UV / 128, N_UV / 128), 256, 0, stream>>>(
      ZU, nullptr, nullptr, nullptr, Z, nullptr, nullptr, v,
      out, nullptr, N_UV, N_UV, NCLASS);
}

// Round 9
// 359.603 us; speedup vs baseline: 1.8118x; 1.1094x over previous
//
#include <hip/hip_runtime.h>
#include <hip/hip_bf16.h>
#include <math.h>

// ---------------------------------------------------------------------------
// Problem constants (from reference)
// ---------------------------------------------------------------------------
#define N_NODES 50000
#define N_EDGES 800000
#define NFEAT   512
#define NHID    256
#define NCLASS  128
#define N_UV    2048

// q24 fixed-point: scale 2^19, range +-16 (|S1|<~5 -> wide margin)
#define Q24_SCALE  524288.0f
#define Q24_INV    1.9073486328125e-6f

typedef __bf16    bf16x8 __attribute__((ext_vector_type(8)));
typedef short     s16x8  __attribute__((ext_vector_type(8)));
typedef float     f32x4  __attribute__((ext_vector_type(4)));

__device__ __forceinline__ unsigned short bf16_rn(float f) {
  unsigned u = __float_as_uint(f);
  u += 0x7fffu + ((u >> 16) & 1u);
  return (unsigned short)(u >> 16);
}
__device__ __forceinline__ float bf16_to_f(unsigned short h) {
  return __uint_as_float(((unsigned)h) << 16);
}

// ---------------------------------------------------------------------------
// Split-bf16 MFMA GEMM: C[M,N] = A[M,K] @ BT[N,K]^T  (fp32-quality via
// Ahi*Bhi + Ahi*Blo + Alo*Bhi; 3-term is REQUIRED — round-6/8 calibration:
// stage-input rms error amplifies ~280x into output absmax).
// 128x128 tile, BK=32, 256 thr, 4 waves 2x2, 4x4 mfma_f32_16x16x32_bf16.
// 2-stage register pipeline: prefetch tile k+1 into VGPRs during compute of
// tile k. launch_bounds(256,2): (256,4) spilled (round-4: WRITE 50->387MB).
// OMODE: 0 = fp32 C, 1 = sigmoid fp32 C, 2 = q24 byte-PLANES to Cq
//        (plane p at Cq + p*M*N; plane layout kills the 12B line-crossing
//         lanes in the downstream gather).
// ---------------------------------------------------------------------------
#define LDSPAD 40   // 32 + 8 shorts: keeps 16B alignment, breaks pow2 stride

template <bool ASPLIT, bool BSPLIT, int OMODE>
__global__ __launch_bounds__(256, 2) void gemm_mfma_split(
    const float* __restrict__ Af,
    const unsigned short* __restrict__ Ahi, const unsigned short* __restrict__ Alo,
    const float* __restrict__ BTf,
    const unsigned short* __restrict__ BThi, const unsigned short* __restrict__ BTlo,
    float* __restrict__ C, unsigned char* __restrict__ Cq, int M, int N, int K) {
  __shared__ unsigned short sAh[128 * LDSPAD];
  __shared__ unsigned short sAl[128 * LDSPAD];
  __shared__ unsigned short sBh[128 * LDSPAD];
  __shared__ unsigned short sBl[128 * LDSPAD];

  const int tid  = threadIdx.x;
  const int lane = tid & 63;
  const int wave = tid >> 6;
  const int wm   = (wave >> 1) << 6;
  const int wn   = (wave & 1) << 6;
  const int lm   = lane & 15;
  const int quad = lane >> 4;
  const int m0   = blockIdx.y * 128;
  const int n0   = blockIdx.x * 128;

  const int r32 = tid >> 3;            // 0..31 (fp32 path: 32 rows/pass)
  const int c32 = (tid & 7) * 4;       // float4 col
  const int r16 = tid >> 2;            // 0..63 (bf16 path: 64 rows/pass)
  const int c16 = (tid & 3) * 8;       // s16x8 col

  float4 pA[4]; s16x8 pAh[2], pAl[2];
  float4 pB[4]; s16x8 pBh[2], pBl[2];

  f32x4 acc[4][4];
#pragma unroll
  for (int i = 0; i < 4; ++i)
#pragma unroll
    for (int j = 0; j < 4; ++j)
#pragma unroll
      for (int r = 0; r < 4; ++r) acc[i][j][r] = 0.f;

#define LOAD_TILE(k0)                                                          \
  do {                                                                         \
    if (ASPLIT) {                                                              \
      _Pragma("unroll") for (int p = 0; p < 4; ++p) {                          \
        const int m = m0 + p * 32 + r32;                                       \
        pA[p] = make_float4(0.f, 0.f, 0.f, 0.f);                               \
        if (m < M) pA[p] = *(const float4*)&Af[(size_t)m * K + (k0) + c32];    \
      }                                                                        \
    } else {                                                                   \
      _Pragma("unroll") for (int p = 0; p < 2; ++p) {                          \
        const int m = m0 + p * 64 + r16;                                       \
        _Pragma("unroll") for (int e = 0; e < 8; ++e) { pAh[p][e] = 0; pAl[p][e] = 0; } \
        if (m < M) {                                                           \
          pAh[p] = *(const s16x8*)&Ahi[(size_t)m * K + (k0) + c16];            \
          pAl[p] = *(const s16x8*)&Alo[(size_t)m * K + (k0) + c16];            \
        }                                                                      \
      }                                                                        \
    }                                                                          \
    if (BSPLIT) {                                                              \
      _Pragma("unroll") for (int p = 0; p < 4; ++p) {                          \
        const int n = n0 + p * 32 + r32;                                       \
        pB[p] = *(const float4*)&BTf[(size_t)n * K + (k0) + c32];              \
      }                                                                        \
    } else {                                                                   \
      _Pragma("unroll") for (int p = 0; p < 2; ++p) {                          \
        pBh[p] = *(const s16x8*)&BThi[(size_t)(n0 + p * 64 + r16) * K + (k0) + c16]; \
        pBl[p] = *(const s16x8*)&BTlo[(size_t)(n0 + p * 64 + r16) * K + (k0) + c16]; \
      }                                                                        \
    }                                                                          \
  } while (0)

#define SPLIT4(v, hv, lv)                                                      \
  hv.x = bf16_rn(v.x); lv.x = bf16_rn(v.x - bf16_to_f(hv.x));                  \
  hv.y = bf16_rn(v.y); lv.y = bf16_rn(v.y - bf16_to_f(hv.y));                  \
  hv.z = bf16_rn(v.z); lv.z = bf16_rn(v.z - bf16_to_f(hv.z));                  \
  hv.w = bf16_rn(v.w); lv.w = bf16_rn(v.w - bf16_to_f(hv.w));

#define STORE_TILE()                                                           \
  do {                                                                         \
    if (ASPLIT) {                                                              \
      _Pragma("unroll") for (int p = 0; p < 4; ++p) {                          \
        ushort4 hv, lv; SPLIT4(pA[p], hv, lv);                                 \
        const int row = p * 32 + r32;                                          \
        *(ushort4*)&sAh[row * LDSPAD + c32] = hv;                              \
        *(ushort4*)&sAl[row * LDSPAD + c32] = lv;                              \
      }                                                                        \
    } else {                                                                   \
      _Pragma("unroll") for (int p = 0; p < 2; ++p) {                          \
        const int row = p * 64 + r16;                                          \
        *(s16x8*)&sAh[row * LDSPAD + c16] = pAh[p];                            \
        *(s16x8*)&sAl[row * LDSPAD + c16] = pAl[p];                            \
      }                                                                        \
    }                                                                          \
    if (BSPLIT) {                                                              \
      _Pragma("unroll") for (int p = 0; p < 4; ++p) {                          \
        ushort4 hv, lv; SPLIT4(pB[p], hv, lv);                                 \
        const int row = p * 32 + r32;                                          \
        *(ushort4*)&sBh[row * LDSPAD + c32] = hv;                              \
        *(ushort4*)&sBl[row * LDSPAD + c32] = lv;                              \
      }                                                                        \
    } else {                                                                   \
      _Pragma("unroll") for (int p = 0; p < 2; ++p) {                          \
        const int row = p * 64 + r16;                                          \
        *(s16x8*)&sBh[row * LDSPAD + c16] = pBh[p];                            \
        *(s16x8*)&sBl[row * LDSPAD + c16] = pBl[p];                            \
      }                                                                        \
    }                                                                          \
  } while (0)

  LOAD_TILE(0);

  for (int k0 = 0; k0 < K; k0 += 32) {
    if (k0) __syncthreads();      // WAR: prior iter's frag reads complete
    STORE_TILE();
    __syncthreads();              // RAW: stores visible
    if (k0 + 32 < K) LOAD_TILE(k0 + 32);   // prefetch next tile (latency hidden)

    bf16x8 aH[4], aL[4], bH[4], bL[4];
#pragma unroll
    for (int i = 0; i < 4; ++i) {
      const int r = wm + i * 16 + lm;
      aH[i] = __builtin_bit_cast(bf16x8, *(const s16x8*)&sAh[r * LDSPAD + quad * 8]);
      aL[i] = __builtin_bit_cast(bf16x8, *(const s16x8*)&sAl[r * LDSPAD + quad * 8]);
    }
#pragma unroll
    for (int j = 0; j < 4; ++j) {
      const int r = wn + j * 16 + lm;
      bH[j] = __builtin_bit_cast(bf16x8, *(const s16x8*)&sBh[r * LDSPAD + quad * 8]);
      bL[j] = __builtin_bit_cast(bf16x8, *(const s16x8*)&sBl[r * LDSPAD + quad * 8]);
    }
#pragma unroll
    for (int i = 0; i < 4; ++i)
#pragma unroll
      for (int j = 0; j < 4; ++j) {
        acc[i][j] = __builtin_amdgcn_mfma_f32_16x16x32_bf16(aH[i], bH[j], acc[i][j], 0, 0, 0);
        acc[i][j] = __builtin_amdgcn_mfma_f32_16x16x32_bf16(aH[i], bL[j], acc[i][j], 0, 0, 0);
        acc[i][j] = __builtin_amdgcn_mfma_f32_16x16x32_bf16(aL[i], bH[j], acc[i][j], 0, 0, 0);
      }
  }

  // ---- epilogue: C/D layout col=lane&15, row=quad*4+reg ----
  const size_t qstride = (size_t)M * N;   // byte-plane stride (OMODE 2)
#pragma unroll
  for (int i = 0; i < 4; ++i)
#pragma unroll
    for (int j = 0; j < 4; ++j) {
      const int col = n0 + wn + j * 16 + lm;
#pragma unroll
      for (int r = 0; r < 4; ++r) {
        const int row = m0 + wm + i * 16 + quad * 4 + r;
        if (row < M) {
          float v = acc[i][j][r];
          if (OMODE == 1) {
            v = 1.f / (1.f + expf(-v));
            C[(size_t)row * N + col] = v;
          } else if (OMODE == 2) {
            int q = __float2int_rn(v * Q24_SCALE);
            q = q > 8388607 ? 8388607 : (q < -8388608 ? -8388608 : q);
            const size_t o = (size_t)row * N + col;
            Cq[o]               = (unsigned char)(q & 0xFF);
            Cq[qstride + o]     = (unsigned char)((q >> 8) & 0xFF);
            Cq[2 * qstride + o] = (unsigned char)((q >> 16) & 0xFF);
          } else {
            C[(size_t)row * N + col] = v;
          }
        }
      }
    }
#undef LOAD_TILE
#undef STORE_TILE
#undef SPLIT4
}

// ---------------------------------------------------------------------------
// Fused prep: row_ptr build (edge-parallel) + W1/W2 transpose+split.
// ---------------------------------------------------------------------------
__global__ __launch_bounds__(256) void prep_all(
    const int* __restrict__ rows, int* __restrict__ row_ptr,
    const float* __restrict__ W1, unsigned short* __restrict__ W1Thi,
    unsigned short* __restrict__ W1Tlo,
    const float* __restrict__ W2, unsigned short* __restrict__ W2Thi,
    unsigned short* __restrict__ W2Tlo) {
  const int idx = blockIdx.x * 256 + threadIdx.x;
  if (idx < N_EDGES) {
    const int r = rows[idx];
    const int rprev = (idx == 0) ? -1 : rows[idx - 1];
    for (int n = rprev + 1; n <= r; ++n) row_ptr[n] = idx;
    if (idx == N_EDGES - 1)
      for (int n = r + 1; n <= N_NODES; ++n) row_ptr[n] = N_EDGES;
  }
  if (idx < NFEAT * NHID) {   // W1T[n*K+k] = split(W1[k*N+n]), K=NFEAT N=NHID
    const int n = idx / NFEAT;
    const int k = idx - n * NFEAT;
    const float f = W1[(size_t)k * NHID + n];
    const unsigned short h = bf16_rn(f);
    W1Thi[idx] = h;
    W1Tlo[idx] = bf16_rn(f - bf16_to_f(h));
  }
  if (idx < NHID * NCLASS) {  // W2T, K=NHID N=NCLASS
    const int n = idx / NHID;
    const int k = idx - n * NHID;
    const float f = W2[(size_t)k * NCLASS + n];
    const unsigned short h = bf16_rn(f);
    W2Thi[idx] = h;
    W2Tlo[idx] = bf16_rn(f - bf16_to_f(h));
  }
}

// ---------------------------------------------------------------------------
// SpMM F=256, q24 PLANE source: per edge, lane loads one dword (4 feats'
// bytes) from each of 3 byte-planes — three aligned 256B segments per edge,
// no line-crossing lanes. 8-edge unroll, fp32 accumulate.
// Fused bias+relu+bf16 hi/lo split output.
// ---------------------------------------------------------------------------
__global__ __launch_bounds__(256) void spmm256_q24p_split(
    const unsigned char* __restrict__ Sq, const int* __restrict__ row_ptr,
    const int* __restrict__ cols, const float* __restrict__ vals,
    const float4* __restrict__ bias4,
    unsigned short* __restrict__ outHi, unsigned short* __restrict__ outLo) {
  const size_t MN = (size_t)N_NODES * NHID;
  const int wave = threadIdx.x >> 6;
  const int lane = threadIdx.x & 63;
  const int node = blockIdx.x * 4 + wave;

  const int lo = row_ptr[node];
  const int hi = row_ptr[node + 1];

  float acc[4] = {0.f, 0.f, 0.f, 0.f};

#define ACCP(d0, d1, d2, ww)                                                   \
  do {                                                                         \
    const float ws = (ww) * Q24_INV;                                           \
    _Pragma("unroll") for (int i = 0; i < 4; ++i) {                            \
      const int q = ((int)((((d2) >> (8 * i)) & 0xFFu) << 24 |                 \
                           (((d1) >> (8 * i)) & 0xFFu) << 16 |                 \
                           (((d0) >> (8 * i)) & 0xFFu) << 8)) >> 8;            \
      acc[i] = fmaf(ws, (float)q, acc[i]);                                     \
    }                                                                          \
  } while (0)

  int e = lo;
  for (; e + 8 <= hi; e += 8) {
    int c[8]; float w[8];
#pragma unroll
    for (int t = 0; t < 8; ++t) { c[t] = cols[e + t]; w[t] = vals[e + t]; }
    unsigned d0[8], d1[8], d2[8];
#pragma unroll
    for (int t = 0; t < 8; ++t) {
      const size_t off = (size_t)c[t] * NHID + lane * 4;
      d0[t] = *(const unsigned*)&Sq[off];
      d1[t] = *(const unsigned*)&Sq[MN + off];
      d2[t] = *(const unsigned*)&Sq[2 * MN + off];
    }
#pragma unroll
    for (int t = 0; t < 8; ++t) ACCP(d0[t], d1[t], d2[t], w[t]);
  }
  for (; e < hi; ++e) {
    const size_t off = (size_t)cols[e] * NHID + lane * 4;
    const unsigned d0 = *(const unsigned*)&Sq[off];
    const unsigned d1 = *(const unsigned*)&Sq[MN + off];
    const unsigned d2 = *(const unsigned*)&Sq[2 * MN + off];
    ACCP(d0, d1, d2, vals[e]);
  }
#undef ACCP

  const float4 b = bias4[lane];
  float4 av;
  av.x = fmaxf(acc[0] + b.x, 0.f);
  av.y = fmaxf(acc[1] + b.y, 0.f);
  av.z = fmaxf(acc[2] + b.z, 0.f);
  av.w = fmaxf(acc[3] + b.w, 0.f);

  ushort4 hv, lv;
  hv.x = bf16_rn(av.x); lv.x = bf16_rn(av.x - bf16_to_f(hv.x));
  hv.y = bf16_rn(av.y); lv.y = bf16_rn(av.y - bf16_to_f(hv.y));
  hv.z = bf16_rn(av.z); lv.z = bf16_rn(av.z - bf16_to_f(hv.z));
  hv.w = bf16_rn(av.w); lv.w = bf16_rn(av.w - bf16_to_f(hv.w));
  const size_t o = (size_t)node * NHID + lane * 4;
  *(ushort4*)&outHi[o] = hv;
  *(ushort4*)&outLo[o] = lv;
}

// ---------------------------------------------------------------------------
// SpMM F=128 over the 4096 LISTED nodes only (concat(u,v)) — the reference
// uses Z only at rows u and v, so the other ~46K rows are dead work.
// One wave per list entry; half-waves alternate edges (32 lanes x float4 =
// full 512B row), 4-edge unroll per half, shfl_xor combine. fp32 out ZUV.
// ---------------------------------------------------------------------------
__global__ __launch_bounds__(256) void spmm128_f32_list(
    const float4* __restrict__ S4, const int* __restrict__ row_ptr,
    const int* __restrict__ cols, const float* __restrict__ vals,
    const float4* __restrict__ bias4,
    const int* __restrict__ u, const int* __restrict__ v,
    float4* __restrict__ out4) {
  const int wave = threadIdx.x >> 6;
  const int lane = threadIdx.x & 63;
  const int half = lane >> 5;
  const int l32  = lane & 31;
  const int idx  = blockIdx.x * 4 + wave;          // 0..4095
  const int node = idx < N_UV ? u[idx] : v[idx - N_UV];

  const int lo = row_ptr[node];
  const int hi = row_ptr[node + 1];

  float4 acc = make_float4(0.f, 0.f, 0.f, 0.f);
  int e = lo + half;
  for (; e + 6 < hi; e += 8) {   // edges e, e+2, e+4, e+6 for this half
    int c[4]; float w[4];
#pragma unroll
    for (int t = 0; t < 4; ++t) { c[t] = cols[e + 2 * t]; w[t] = vals[e + 2 * t]; }
    float4 r[4];
#pragma unroll
    for (int t = 0; t < 4; ++t) r[t] = S4[(size_t)c[t] * 32 + l32];
#pragma unroll
    for (int t = 0; t < 4; ++t) {
      acc.x = fmaf(w[t], r[t].x, acc.x); acc.y = fmaf(w[t], r[t].y, acc.y);
      acc.z = fmaf(w[t], r[t].z, acc.z); acc.w = fmaf(w[t], r[t].w, acc.w);
    }
  }
  for (; e < hi; e += 2) {
    const int c = cols[e];
    const float w = vals[e];
    const float4 r = S4[(size_t)c * 32 + l32];
    acc.x = fmaf(w, r.x, acc.x); acc.y = fmaf(w, r.y, acc.y);
    acc.z = fmaf(w, r.z, acc.z); acc.w = fmaf(w, r.w, acc.w);
  }

  acc.x += __shfl_xor(acc.x, 32);
  acc.y += __shfl_xor(acc.y, 32);
  acc.z += __shfl_xor(acc.z, 32);
  acc.w += __shfl_xor(acc.w, 32);

  if (half == 0) {
    const float4 b = bias4[l32];
    acc.x += b.x; acc.y += b.y; acc.z += b.z; acc.w += b.w;
    out4[(size_t)idx * 32 + l32] = acc;
  }
}

// ---------------------------------------------------------------------------
// Launch
// ---------------------------------------------------------------------------
extern "C" void kernel_launch(void* const* d_in, const int* in_sizes, int n_in,
                              void* d_out, int out_size, void* d_ws, size_t ws_size,
                              hipStream_t stream) {
  const int*   u       = (const int*)  d_in[0];
  const int*   v       = (const int*)  d_in[1];
  const float* x       = (const float*)d_in[2];
  const int*   adj_row = (const int*)  d_in[3];
  const int*   adj_col = (const int*)  d_in[4];
  const float* adj_val = (const float*)d_in[5];
  const float* W1      = (const float*)d_in[6];
  const float* b1      = (const float*)d_in[7];
  const float* W2      = (const float*)d_in[8];
  const float* b2      = (const float*)d_in[9];
  const float* We      = (const float*)d_in[10];
  float* out = (float*)d_out;

  char* wsb = (char*)d_ws;
  // Region A [0, 51.2MB):
  //   S1q byte-planes 3 x 12.8MB at [0, 38.4MB)
  //   after spmm1: S2 fp32 [0, 25.6MB), ZUV fp32 [25.6, 27.7MB)
  unsigned char* S1q = (unsigned char*)wsb;
  float* S2  = (float*)wsb;
  float* ZUV = (float*)(wsb + (size_t)N_NODES * NCLASS * sizeof(float));
  // Region B [51.2MB, 102.4MB): Hhi/Hlo; after GEMM2 dead -> ZU
  char* rB = wsb + (size_t)N_NODES * NHID * sizeof(float);
  unsigned short* Hhi = (unsigned short*)rB;
  unsigned short* Hlo = Hhi + (size_t)N_NODES * NHID;
  float* ZU = (float*)rB;                  // 2048*128
  // Split weights + row_ptr parked in d_out (dead until the final GEMM)
  unsigned short* W1Thi = (unsigned short*)out;
  unsigned short* W1Tlo = W1Thi + NHID * NFEAT;
  unsigned short* W2Thi = W1Tlo + NHID * NFEAT;
  unsigned short* W2Tlo = W2Thi + NCLASS * NHID;
  int* row_ptr = (int*)(W2Tlo + NCLASS * NHID);   // 50001 ints

  // 0) fused prep: row_ptr + weight transpose/split (one launch)
  prep_all<<<(N_EDGES + 255) / 256, 256, 0, stream>>>(
      adj_row, row_ptr, W1, W1Thi, W1Tlo, W2, W2Thi, W2Tlo);

  // 1) S1q = q24-planes(x @ W1)  (MFMA split-bf16, A split on the fly)
  gemm_mfma_split<true, false, 2>
      <<<dim3(NHID / 128, (N_NODES + 127) / 128), 256, 0, stream>>>(
      x, nullptr, nullptr, nullptr, W1Thi, W1Tlo,
      nullptr, S1q, N_NODES, NHID, NFEAT);

  // 2) Hhi/Hlo = split(relu(A @ S1 + b1))   (q24 plane gather)
  spmm256_q24p_split<<<N_NODES / 4, 256, 0, stream>>>(
      S1q, row_ptr, adj_col, adj_val, (const float4*)b1, Hhi, Hlo);

  // 3) S2 = H @ W2  (MFMA split-bf16, A pre-split, fp32 out)
  gemm_mfma_split<false, false, 0>
      <<<dim3(NCLASS / 128, (N_NODES + 127) / 128), 256, 0, stream>>>(
      nullptr, Hhi, Hlo, nullptr, W2Thi, W2Tlo,
      S2, nullptr, N_NODES, NCLASS, NHID);

  // 4) ZUV = (A @ S2 + b2)[concat(u,v)]  — only the 4096 rows the head uses
  spmm128_f32_list<<<(2 * N_UV) / 4, 256, 0, stream>>>(
      (const float4*)S2, row_ptr, adj_col, adj_val, (const float4*)b2,
      u, v, (float4*)ZUV);

  // 5) ZU = ZUV[0:2048] @ We^T  (BT = We as stored)
  gemm_mfma_split<true, true, 0>
      <<<dim3(NCLASS / 128, N_UV / 128), 256, 0, stream>>>(
      ZUV, nullptr, nullptr, We, nullptr, nullptr,
      ZU, nullptr, N_UV, NCLASS, NCLASS);

  // 6) out = sigmoid(ZU @ ZUV[2048:4096]^T)
  gemm_mfma_split<true, true, 1>
      <<<dim3(N_UV / 128, N_UV / 128), 256, 0, stream>>>(
      ZU, nullptr, nullptr, ZUV + (size_t)N_UV * NCLASS, nullptr, nullptr,
      out, nullptr, N_UV, N_UV, NCLASS);
}

// Round 10
// 355.372 us; speedup vs baseline: 1.8333x; 1.0119x over previous
//
#include <hip/hip_runtime.h>
#include <hip/hip_bf16.h>
#include <math.h>

// ---------------------------------------------------------------------------
// Problem constants (from reference)
// ---------------------------------------------------------------------------
#define N_NODES 50000
#define N_EDGES 800000
#define NFEAT   512
#define NHID    256
#define NCLASS  128
#define N_UV    2048

// q24 fixed-point: scale 2^19, range +-16 (|S1|<~5 -> wide margin)
#define Q24_SCALE  524288.0f
#define Q24_INV    1.9073486328125e-6f

typedef __bf16    bf16x8 __attribute__((ext_vector_type(8)));
typedef short     s16x8  __attribute__((ext_vector_type(8)));
typedef float     f32x4  __attribute__((ext_vector_type(4)));

struct __attribute__((packed)) U3 { unsigned a, b, c; };  // 12B dwordx3 view

__device__ __forceinline__ unsigned short bf16_rn(float f) {
  unsigned u = __float_as_uint(f);
  u += 0x7fffu + ((u >> 16) & 1u);
  return (unsigned short)(u >> 16);
}
__device__ __forceinline__ float bf16_to_f(unsigned short h) {
  return __uint_as_float(((unsigned)h) << 16);
}
// 4 x 24-bit signed little-endian values from 3 dwords
__device__ __forceinline__ void unpack24(unsigned a, unsigned b, unsigned c,
                                         int& e0, int& e1, int& e2, int& e3) {
  e0 = ((int)(a << 8)) >> 8;
  e1 = ((int)((b << 16) | ((a >> 24) << 8))) >> 8;
  e2 = ((int)((c << 24) | ((b >> 16) << 8))) >> 8;
  e3 = ((int)c) >> 8;
}

// ---------------------------------------------------------------------------
// Split-bf16 MFMA GEMM: C[M,N] = A[M,K] @ BT[N,K]^T  (fp32-quality via
// Ahi*Bhi + Ahi*Blo + Alo*Bhi; 3-term REQUIRED — r6/r8 calibration: stage
// rms error amplifies ~280x into output absmax).
// 128x128 tile, BK=64 (r10: halves barrier count vs BK=32; 96 MFMA/barrier;
// occupancy unchanged at 2 blocks/CU — VGPR-pinned), 256 thr, 4 waves 2x2,
// 4x4 mfma_f32_16x16x32_bf16 x 2 K-substeps.
// 2-stage register pipeline: prefetch tile k+1 into VGPRs during compute of
// tile k. launch_bounds(256,2): (256,4) spilled (round-4: WRITE 50->387MB).
// OMODE: 0 = fp32 C, 1 = sigmoid fp32 C, 2 = interleaved q24 (3B/elem).
// ---------------------------------------------------------------------------
#define LDSPAD 72   // 64 + 8 shorts: keeps 16B alignment, breaks pow2 stride

template <bool ASPLIT, bool BSPLIT, int OMODE>
__global__ __launch_bounds__(256, 2) void gemm_mfma_split(
    const float* __restrict__ Af,
    const unsigned short* __restrict__ Ahi, const unsigned short* __restrict__ Alo,
    const float* __restrict__ BTf,
    const unsigned short* __restrict__ BThi, const unsigned short* __restrict__ BTlo,
    float* __restrict__ C, unsigned char* __restrict__ Cq, int M, int N, int K) {
  __shared__ unsigned short sAh[128 * LDSPAD];
  __shared__ unsigned short sAl[128 * LDSPAD];
  __shared__ unsigned short sBh[128 * LDSPAD];
  __shared__ unsigned short sBl[128 * LDSPAD];

  const int tid  = threadIdx.x;
  const int lane = tid & 63;
  const int wave = tid >> 6;
  const int wm   = (wave >> 1) << 6;
  const int wn   = (wave & 1) << 6;
  const int lm   = lane & 15;
  const int quad = lane >> 4;
  const int m0   = blockIdx.y * 128;
  const int n0   = blockIdx.x * 128;

  // staging coordinates (BK=64)
  const int r32 = tid >> 4;            // 0..15 (fp32 path: 16 rows/pass, 8 passes)
  const int c32 = (tid & 15) * 4;      // float4 col 0..60
  const int r16 = tid >> 3;            // 0..31 (bf16 path: 32 rows/pass, 4 passes)
  const int c16 = (tid & 7) * 8;       // s16x8 col 0..56

  float4 pA[8]; s16x8 pAh[4], pAl[4];
  float4 pB[8]; s16x8 pBh[4], pBl[4];

  f32x4 acc[4][4];
#pragma unroll
  for (int i = 0; i < 4; ++i)
#pragma unroll
    for (int j = 0; j < 4; ++j)
#pragma unroll
      for (int r = 0; r < 4; ++r) acc[i][j][r] = 0.f;

#define LOAD_TILE(k0)                                                          \
  do {                                                                         \
    if (ASPLIT) {                                                              \
      _Pragma("unroll") for (int p = 0; p < 8; ++p) {                          \
        const int m = m0 + p * 16 + r32;                                       \
        pA[p] = make_float4(0.f, 0.f, 0.f, 0.f);                               \
        if (m < M) pA[p] = *(const float4*)&Af[(size_t)m * K + (k0) + c32];    \
      }                                                                        \
    } else {                                                                   \
      _Pragma("unroll") for (int p = 0; p < 4; ++p) {                          \
        const int m = m0 + p * 32 + r16;                                       \
        _Pragma("unroll") for (int e = 0; e < 8; ++e) { pAh[p][e] = 0; pAl[p][e] = 0; } \
        if (m < M) {                                                           \
          pAh[p] = *(const s16x8*)&Ahi[(size_t)m * K + (k0) + c16];            \
          pAl[p] = *(const s16x8*)&Alo[(size_t)m * K + (k0) + c16];            \
        }                                                                      \
      }                                                                        \
    }                                                                          \
    if (BSPLIT) {                                                              \
      _Pragma("unroll") for (int p = 0; p < 8; ++p) {                          \
        const int n = n0 + p * 16 + r32;                                       \
        pB[p] = *(const float4*)&BTf[(size_t)n * K + (k0) + c32];              \
      }                                                                        \
    } else {                                                                   \
      _Pragma("unroll") for (int p = 0; p < 4; ++p) {                          \
        pBh[p] = *(const s16x8*)&BThi[(size_t)(n0 + p * 32 + r16) * K + (k0) + c16]; \
        pBl[p] = *(const s16x8*)&BTlo[(size_t)(n0 + p * 32 + r16) * K + (k0) + c16]; \
      }                                                                        \
    }                                                                          \
  } while (0)

#define SPLIT4(v, hv, lv)                                                      \
  hv.x = bf16_rn(v.x); lv.x = bf16_rn(v.x - bf16_to_f(hv.x));                  \
  hv.y = bf16_rn(v.y); lv.y = bf16_rn(v.y - bf16_to_f(hv.y));                  \
  hv.z = bf16_rn(v.z); lv.z = bf16_rn(v.z - bf16_to_f(hv.z));                  \
  hv.w = bf16_rn(v.w); lv.w = bf16_rn(v.w - bf16_to_f(hv.w));

#define STORE_TILE()                                                           \
  do {                                                                         \
    if (ASPLIT) {                                                              \
      _Pragma("unroll") for (int p = 0; p < 8; ++p) {                          \
        ushort4 hv, lv; SPLIT4(pA[p], hv, lv);                                 \
        const int row = p * 16 + r32;                                          \
        *(ushort4*)&sAh[row * LDSPAD + c32] = hv;                              \
        *(ushort4*)&sAl[row * LDSPAD + c32] = lv;                              \
      }                                                                        \
    } else {                                                                   \
      _Pragma("unroll") for (int p = 0; p < 4; ++p) {                          \
        const int row = p * 32 + r16;                                          \
        *(s16x8*)&sAh[row * LDSPAD + c16] = pAh[p];                            \
        *(s16x8*)&sAl[row * LDSPAD + c16] = pAl[p];                            \
      }                                                                        \
    }                                                                          \
    if (BSPLIT) {                                                              \
      _Pragma("unroll") for (int p = 0; p < 8; ++p) {                          \
        ushort4 hv, lv; SPLIT4(pB[p], hv, lv);                                 \
        const int row = p * 16 + r32;                                          \
        *(ushort4*)&sBh[row * LDSPAD + c32] = hv;                              \
        *(ushort4*)&sBl[row * LDSPAD + c32] = lv;                              \
      }                                                                        \
    } else {                                                                   \
      _Pragma("unroll") for (int p = 0; p < 4; ++p) {                          \
        const int row = p * 32 + r16;                                          \
        *(s16x8*)&sBh[row * LDSPAD + c16] = pBh[p];                            \
        *(s16x8*)&sBl[row * LDSPAD + c16] = pBl[p];                            \
      }                                                                        \
    }                                                                          \
  } while (0)

  LOAD_TILE(0);

  for (int k0 = 0; k0 < K; k0 += 64) {
    if (k0) __syncthreads();      // WAR: prior iter's frag reads complete
    STORE_TILE();
    __syncthreads();              // RAW: stores visible
    if (k0 + 64 < K) LOAD_TILE(k0 + 64);   // prefetch next tile

#pragma unroll
    for (int ks = 0; ks < 2; ++ks) {
      const int koff = ks * 32 + quad * 8;
      bf16x8 aH[4], aL[4], bH[4], bL[4];
#pragma unroll
      for (int i = 0; i < 4; ++i) {
        const int r = wm + i * 16 + lm;
        aH[i] = __builtin_bit_cast(bf16x8, *(const s16x8*)&sAh[r * LDSPAD + koff]);
        aL[i] = __builtin_bit_cast(bf16x8, *(const s16x8*)&sAl[r * LDSPAD + koff]);
      }
#pragma unroll
      for (int j = 0; j < 4; ++j) {
        const int r = wn + j * 16 + lm;
        bH[j] = __builtin_bit_cast(bf16x8, *(const s16x8*)&sBh[r * LDSPAD + koff]);
        bL[j] = __builtin_bit_cast(bf16x8, *(const s16x8*)&sBl[r * LDSPAD + koff]);
      }
#pragma unroll
      for (int i = 0; i < 4; ++i)
#pragma unroll
        for (int j = 0; j < 4; ++j) {
          acc[i][j] = __builtin_amdgcn_mfma_f32_16x16x32_bf16(aH[i], bH[j], acc[i][j], 0, 0, 0);
          acc[i][j] = __builtin_amdgcn_mfma_f32_16x16x32_bf16(aH[i], bL[j], acc[i][j], 0, 0, 0);
          acc[i][j] = __builtin_amdgcn_mfma_f32_16x16x32_bf16(aL[i], bH[j], acc[i][j], 0, 0, 0);
        }
    }
  }

  // ---- epilogue: C/D layout col=lane&15, row=quad*4+reg ----
#pragma unroll
  for (int i = 0; i < 4; ++i)
#pragma unroll
    for (int j = 0; j < 4; ++j) {
      const int col = n0 + wn + j * 16 + lm;
#pragma unroll
      for (int r = 0; r < 4; ++r) {
        const int row = m0 + wm + i * 16 + quad * 4 + r;
        if (row < M) {
          float v = acc[i][j][r];
          if (OMODE == 1) {
            v = 1.f / (1.f + expf(-v));
            C[(size_t)row * N + col] = v;
          } else if (OMODE == 2) {
            int q = __float2int_rn(v * Q24_SCALE);
            q = q > 8388607 ? 8388607 : (q < -8388608 ? -8388608 : q);
            unsigned char* p = Cq + ((size_t)row * N + col) * 3;
            p[0] = (unsigned char)(q & 0xFF);
            p[1] = (unsigned char)((q >> 8) & 0xFF);
            p[2] = (unsigned char)((q >> 16) & 0xFF);
          } else {
            C[(size_t)row * N + col] = v;
          }
        }
      }
    }
#undef LOAD_TILE
#undef STORE_TILE
#undef SPLIT4
}

// ---------------------------------------------------------------------------
// Fused prep: row_ptr build (edge-parallel) + W1/W2 transpose+split.
// ---------------------------------------------------------------------------
__global__ __launch_bounds__(256) void prep_all(
    const int* __restrict__ rows, int* __restrict__ row_ptr,
    const float* __restrict__ W1, unsigned short* __restrict__ W1Thi,
    unsigned short* __restrict__ W1Tlo,
    const float* __restrict__ W2, unsigned short* __restrict__ W2Thi,
    unsigned short* __restrict__ W2Tlo) {
  const int idx = blockIdx.x * 256 + threadIdx.x;
  if (idx < N_EDGES) {
    const int r = rows[idx];
    const int rprev = (idx == 0) ? -1 : rows[idx - 1];
    for (int n = rprev + 1; n <= r; ++n) row_ptr[n] = idx;
    if (idx == N_EDGES - 1)
      for (int n = r + 1; n <= N_NODES; ++n) row_ptr[n] = N_EDGES;
  }
  if (idx < NFEAT * NHID) {   // W1T[n*K+k] = split(W1[k*N+n]), K=NFEAT N=NHID
    const int n = idx / NFEAT;
    const int k = idx - n * NFEAT;
    const float f = W1[(size_t)k * NHID + n];
    const unsigned short h = bf16_rn(f);
    W1Thi[idx] = h;
    W1Tlo[idx] = bf16_rn(f - bf16_to_f(h));
  }
  if (idx < NHID * NCLASS) {  // W2T, K=NHID N=NCLASS
    const int n = idx / NHID;
    const int k = idx - n * NHID;
    const float f = W2[(size_t)k * NCLASS + n];
    const unsigned short h = bf16_rn(f);
    W2Thi[idx] = h;
    W2Tlo[idx] = bf16_rn(f - bf16_to_f(h));
  }
}

// ---------------------------------------------------------------------------
// SpMM F=256, interleaved q24 source (768B rows): one wave per node, lane =
// 12B dwordx3 = 4 elems (full row per wave), 8-edge unroll. fp32 accumulate.
// Fused bias+relu+bf16 hi/lo split output.  (r9 plane-split regressed:
// VALU 27->60%; interleaved is the measured best at 88.7us.)
// ---------------------------------------------------------------------------
__global__ __launch_bounds__(256) void spmm256_q24_split(
    const unsigned char* __restrict__ Sq, const int* __restrict__ row_ptr,
    const int* __restrict__ cols, const float* __restrict__ vals,
    const float4* __restrict__ bias4,
    unsigned short* __restrict__ outHi, unsigned short* __restrict__ outLo) {
  const int wave = threadIdx.x >> 6;
  const int lane = threadIdx.x & 63;
  const int node = blockIdx.x * 4 + wave;

  const int lo = row_ptr[node];
  const int hi = row_ptr[node + 1];

  float4 acc = make_float4(0.f, 0.f, 0.f, 0.f);

#define ACCQ(dd, ww)                                                           \
  do {                                                                         \
    int e0, e1, e2, e3;                                                        \
    unpack24((dd).a, (dd).b, (dd).c, e0, e1, e2, e3);                          \
    const float ws = (ww) * Q24_INV;                                           \
    acc.x = fmaf(ws, (float)e0, acc.x);                                        \
    acc.y = fmaf(ws, (float)e1, acc.y);                                        \
    acc.z = fmaf(ws, (float)e2, acc.z);                                        \
    acc.w = fmaf(ws, (float)e3, acc.w);                                        \
  } while (0)

  int e = lo;
  for (; e + 8 <= hi; e += 8) {
    int c[8]; float w[8];
#pragma unroll
    for (int t = 0; t < 8; ++t) { c[t] = cols[e + t]; w[t] = vals[e + t]; }
    U3 d[8];
#pragma unroll
    for (int t = 0; t < 8; ++t)
      d[t] = *(const U3*)&Sq[(size_t)c[t] * (NHID * 3) + lane * 12];
#pragma unroll
    for (int t = 0; t < 8; ++t) ACCQ(d[t], w[t]);
  }
  for (; e < hi; ++e) {
    const U3 d = *(const U3*)&Sq[(size_t)cols[e] * (NHID * 3) + lane * 12];
    ACCQ(d, vals[e]);
  }
#undef ACCQ

  const float4 b = bias4[lane];
  acc.x = fmaxf(acc.x + b.x, 0.f);
  acc.y = fmaxf(acc.y + b.y, 0.f);
  acc.z = fmaxf(acc.z + b.z, 0.f);
  acc.w = fmaxf(acc.w + b.w, 0.f);

  ushort4 hv, lv;
  hv.x = bf16_rn(acc.x); lv.x = bf16_rn(acc.x - bf16_to_f(hv.x));
  hv.y = bf16_rn(acc.y); lv.y = bf16_rn(acc.y - bf16_to_f(hv.y));
  hv.z = bf16_rn(acc.z); lv.z = bf16_rn(acc.z - bf16_to_f(hv.z));
  hv.w = bf16_rn(acc.w); lv.w = bf16_rn(acc.w - bf16_to_f(hv.w));
  const size_t o = (size_t)node * NHID + lane * 4;
  *(ushort4*)&outHi[o] = hv;
  *(ushort4*)&outLo[o] = lv;
}

// ---------------------------------------------------------------------------
// SpMM F=128 over the 4096 LISTED nodes only (concat(u,v)) — Z is consumed
// only at rows u,v. One wave per list entry; half-waves alternate edges
// (32 lanes x float4 = full 512B row), 4-edge unroll per half. fp32 out ZUV.
// ---------------------------------------------------------------------------
__global__ __launch_bounds__(256) void spmm128_f32_list(
    const float4* __restrict__ S4, const int* __restrict__ row_ptr,
    const int* __restrict__ cols, const float* __restrict__ vals,
    const float4* __restrict__ bias4,
    const int* __restrict__ u, const int* __restrict__ v,
    float4* __restrict__ out4) {
  const int wave = threadIdx.x >> 6;
  const int lane = threadIdx.x & 63;
  const int half = lane >> 5;
  const int l32  = lane & 31;
  const int idx  = blockIdx.x * 4 + wave;          // 0..4095
  const int node = idx < N_UV ? u[idx] : v[idx - N_UV];

  const int lo = row_ptr[node];
  const int hi = row_ptr[node + 1];

  float4 acc = make_float4(0.f, 0.f, 0.f, 0.f);
  int e = lo + half;
  for (; e + 6 < hi; e += 8) {   // edges e, e+2, e+4, e+6 for this half
    int c[4]; float w[4];
#pragma unroll
    for (int t = 0; t < 4; ++t) { c[t] = cols[e + 2 * t]; w[t] = vals[e + 2 * t]; }
    float4 r[4];
#pragma unroll
    for (int t = 0; t < 4; ++t) r[t] = S4[(size_t)c[t] * 32 + l32];
#pragma unroll
    for (int t = 0; t < 4; ++t) {
      acc.x = fmaf(w[t], r[t].x, acc.x); acc.y = fmaf(w[t], r[t].y, acc.y);
      acc.z = fmaf(w[t], r[t].z, acc.z); acc.w = fmaf(w[t], r[t].w, acc.w);
    }
  }
  for (; e < hi; e += 2) {
    const int c = cols[e];
    const float w = vals[e];
    const float4 r = S4[(size_t)c * 32 + l32];
    acc.x = fmaf(w, r.x, acc.x); acc.y = fmaf(w, r.y, acc.y);
    acc.z = fmaf(w, r.z, acc.z); acc.w = fmaf(w, r.w, acc.w);
  }

  acc.x += __shfl_xor(acc.x, 32);
  acc.y += __shfl_xor(acc.y, 32);
  acc.z += __shfl_xor(acc.z, 32);
  acc.w += __shfl_xor(acc.w, 32);

  if (half == 0) {
    const float4 b = bias4[l32];
    acc.x += b.x; acc.y += b.y; acc.z += b.z; acc.w += b.w;
    out4[(size_t)idx * 32 + l32] = acc;
  }
}

// ---------------------------------------------------------------------------
// Launch
// ---------------------------------------------------------------------------
extern "C" void kernel_launch(void* const* d_in, const int* in_sizes, int n_in,
                              void* d_out, int out_size, void* d_ws, size_t ws_size,
                              hipStream_t stream) {
  const int*   u       = (const int*)  d_in[0];
  const int*   v       = (const int*)  d_in[1];
  const float* x       = (const float*)d_in[2];
  const int*   adj_row = (const int*)  d_in[3];
  const int*   adj_col = (const int*)  d_in[4];
  const float* adj_val = (const float*)d_in[5];
  const float* W1      = (const float*)d_in[6];
  const float* b1      = (const float*)d_in[7];
  const float* W2      = (const float*)d_in[8];
  const float* b2      = (const float*)d_in[9];
  const float* We      = (const float*)d_in[10];
  float* out = (float*)d_out;

  char* wsb = (char*)d_ws;
  // Region A [0, 51.2MB):
  //   S1q interleaved q24 38.4MB at [0, 38.4MB)
  //   after spmm1: S2 fp32 [0, 25.6MB), ZUV fp32 [25.6, 27.7MB)
  unsigned char* S1q = (unsigned char*)wsb;
  float* S2  = (float*)wsb;
  float* ZUV = (float*)(wsb + (size_t)N_NODES * NCLASS * sizeof(float));
  // Region B [51.2MB, 102.4MB): Hhi/Hlo; after GEMM2 dead -> ZU
  char* rB = wsb + (size_t)N_NODES * NHID * sizeof(float);
  unsigned short* Hhi = (unsigned short*)rB;
  unsigned short* Hlo = Hhi + (size_t)N_NODES * NHID;
  float* ZU = (float*)rB;                  // 2048*128
  // Split weights + row_ptr parked in d_out (dead until the final GEMM)
  unsigned short* W1Thi = (unsigned short*)out;
  unsigned short* W1Tlo = W1Thi + NHID * NFEAT;
  unsigned short* W2Thi = W1Tlo + NHID * NFEAT;
  unsigned short* W2Tlo = W2Thi + NCLASS * NHID;
  int* row_ptr = (int*)(W2Tlo + NCLASS * NHID);   // 50001 ints

  // 0) fused prep: row_ptr + weight transpose/split (one launch)
  prep_all<<<(N_EDGES + 255) / 256, 256, 0, stream>>>(
      adj_row, row_ptr, W1, W1Thi, W1Tlo, W2, W2Thi, W2Tlo);

  // 1) S1q = q24(x @ W1)  (MFMA split-bf16, BK=64, A split on the fly)
  gemm_mfma_split<true, false, 2>
      <<<dim3(NHID / 128, (N_NODES + 127) / 128), 256, 0, stream>>>(
      x, nullptr, nullptr, nullptr, W1Thi, W1Tlo,
      nullptr, S1q, N_NODES, NHID, NFEAT);

  // 2) Hhi/Hlo = split(relu(A @ S1 + b1))   (interleaved q24 gather)
  spmm256_q24_split<<<N_NODES / 4, 256, 0, stream>>>(
      S1q, row_ptr, adj_col, adj_val, (const float4*)b1, Hhi, Hlo);

  // 3) S2 = H @ W2  (MFMA split-bf16, BK=64, A pre-split, fp32 out)
  gemm_mfma_split<false, false, 0>
      <<<dim3(NCLASS / 128, (N_NODES + 127) / 128), 256, 0, stream>>>(
      nullptr, Hhi, Hlo, nullptr, W2Thi, W2Tlo,
      S2, nullptr, N_NODES, NCLASS, NHID);

  // 4) ZUV = (A @ S2 + b2)[concat(u,v)]  — only the 4096 rows the head uses
  spmm128_f32_list<<<(2 * N_UV) / 4, 256, 0, stream>>>(
      (const float4*)S2, row_ptr, adj_col, adj_val, (const float4*)b2,
      u, v, (float4*)ZUV);

  // 5) ZU = ZUV[0:2048] @ We^T  (BT = We as stored)
  gemm_mfma_split<true, true, 0>
      <<<dim3(NCLASS / 128, N_UV / 128), 256, 0, stream>>>(
      ZUV, nullptr, nullptr, We, nullptr, nullptr,
      ZU, nullptr, N_UV, NCLASS, NCLASS);

  // 6) out = sigmoid(ZU @ ZUV[2048:4096]^T)
  gemm_mfma_split<true, true, 1>
      <<<dim3(N_UV / 128, N_UV / 128), 256, 0, stream>>>(
      ZU, nullptr, nullptr, ZUV + (size_t)N_UV * NCLASS, nullptr, nullptr,
      out, nullptr, N_UV, N_UV, NCLASS);
}